// Round 1
// 1144.500 us; speedup vs baseline: 1.2674x; 1.2674x over previous
//
#include <hip/hip_runtime.h>
#include <math.h>

// ---------------- problem constants ----------------
#define N_NODES 100000
#define N_EDGES 400000
#define IN_CH   100
#define OUT_CH  100
#define HEADS   2
#define HC      200      // HEADS*OUT_CH
#define TIME_DIM 100
#define MSG_DIM  100
#define EDGE_DIM 200
// padded GEMM dims
#define KP_NODE 128      // IN_CH padded to mult of 32
#define KP_EDGE 224      // EDGE_DIM padded to mult of 32
#define NP_EDGE 208      // HC padded to mult of 16 (13 n-tiles)
#define PAD_HC  256      // q/k rows padded: head h at h*128, cols 100..127/228..255 zero
#define EW      264      // e_lds row stride in bf16 elems (528 B)
// node-gemm slab blocking: 4 slabs (q|k|v|skip) x 13 n-tiles (208 cols), 128-node chunks
#define NSLAB_ELEMS (13 * 16 * KP_NODE)   // 26624 bf16 per slab
#define W4T_ELEMS   (4 * NSLAB_ELEMS)     // 106496
#define M_CHUNK 128
#define NCHUNK  782                        // ceil(100000/128)

typedef __attribute__((ext_vector_type(8))) short bf16x8_t;
typedef __attribute__((ext_vector_type(4))) float f32x4_t;

struct __align__(8) us4 { unsigned short x, y, z, w; };

static __device__ __forceinline__ float b2f(unsigned short u){
  union { float f; unsigned int i; } v; v.i = ((unsigned int)u) << 16; return v.f;
}
static __device__ __forceinline__ unsigned short f2b(float f){
  union { float f; unsigned int i; } v; v.f = f;
  unsigned int x = v.i;
  return (unsigned short)((x + 0x7fffu + ((x >> 16) & 1u)) >> 16);
}

// ---------------- pack weights ----------------
// W4T: [slab][tile i][j 0..15][k 0..127] bf16, slab = q|k|v|skip, col = i*16+j (208, top 8 zero)
// bias4: [slab][208] fp32
__global__ __launch_bounds__(256) void pack_weights(
    const float* __restrict__ Wq, const float* __restrict__ bq,
    const float* __restrict__ Wk, const float* __restrict__ bk,
    const float* __restrict__ Wv, const float* __restrict__ bv,
    const float* __restrict__ We, const float* __restrict__ Ws, const float* __restrict__ bs,
    unsigned short* __restrict__ W4T, unsigned short* __restrict__ WeT,
    float* __restrict__ bias4)
{
  int idx = blockIdx.x * 256 + threadIdx.x;
  if (idx < W4T_ELEMS) {
    int row = idx >> 7;          // 0..831 = t*16 + j
    int k   = idx & 127;
    int t = row >> 4, j = row & 15;
    int slab = t / 13, i = t % 13;
    int col = i * 16 + j;        // 0..207
    float v = 0.f;
    if (k < IN_CH && col < HC) {
      const float* W = (slab == 0) ? Wq : (slab == 1) ? Wk : (slab == 2) ? Wv : Ws;
      v = W[k * HC + col];
    }
    W4T[idx] = f2b(v);
    return;
  }
  int j = idx - W4T_ELEMS;
  if (j < NP_EDGE * KP_EDGE) {                 // WeT[n][k]
    int n = j / KP_EDGE, k = j % KP_EDGE;
    float v = 0.f;
    if (n < HC && k < EDGE_DIM) v = We[k * HC + n];
    WeT[j] = f2b(v);
    return;
  }
  j -= NP_EDGE * KP_EDGE;
  if (j < 4 * 208) {
    int slab = j / 208, col = j % 208;
    const float* B = (slab == 0) ? bq : (slab == 1) ? bk : (slab == 2) ? bv : bs;
    bias4[j] = (col < HC) ? B[col] : 0.f;
  }
}

// ---------------- node GEMM: 128-node chunk x one 208-col slab per block ----------------
// blockIdx = chunk*4 + slab; 4 waves each own 32 rows (2 m16-groups x 13 n-tiles).
// Per-block W footprint = 53 KB (stays L2-hot); x chunk read by the 4 co-scheduled slab
// blocks nearly simultaneously (L2/L3 hits for 3 of 4).
__global__ __launch_bounds__(256) void node_gemm(
    const float* __restrict__ x, const unsigned short* __restrict__ W4T,
    const float* __restrict__ bias4,
    unsigned short* __restrict__ q_b, unsigned short* __restrict__ k_b,
    unsigned short* __restrict__ v_b, float* __restrict__ out)
{
  __shared__ __align__(16) unsigned char smem[34816];  // xt[128][136] bf16, reused for staging
  unsigned short* xt = (unsigned short*)smem;

  const int tid   = threadIdx.x;
  const int slab  = blockIdx.x & 3;
  const int chunk = blockIdx.x >> 2;
  const int n0    = chunk * M_CHUNK;
  const int nrows = (N_NODES - n0 < M_CHUNK) ? (N_NODES - n0) : M_CHUNK;

  // stage x chunk (float4 loads), zero rows >= nrows, zero-pad cols 100..127
  for (int idx = tid; idx < 3200; idx += 256) {        // 128 rows * 25 float4
    int r = idx / 25, j = (idx % 25) * 4;
    unsigned short* dst = xt + r * 136 + j;
    if (r < nrows) {
      float4 xv = *reinterpret_cast<const float4*>(x + (size_t)(n0 + r) * IN_CH + j);
      dst[0] = f2b(xv.x); dst[1] = f2b(xv.y); dst[2] = f2b(xv.z); dst[3] = f2b(xv.w);
    } else {
      us4 z = {0, 0, 0, 0};
      *reinterpret_cast<us4*>(dst) = z;
    }
  }
  for (int idx = tid; idx < 896; idx += 256) {         // 128 rows * 7 us4 pad
    int r = idx / 7, j = idx % 7;
    us4 z = {0, 0, 0, 0};
    *reinterpret_cast<us4*>(&xt[r * 136 + 100 + j * 4]) = z;
  }
  __syncthreads();

  const int lane = tid & 63, wave = tid >> 6;
  const int m16 = lane & 15, quad = lane >> 4;
  const int rb = wave * 32;

  float bias_v[13];
  #pragma unroll
  for (int i = 0; i < 13; i++) bias_v[i] = bias4[slab * 208 + i * 16 + m16];

  f32x4_t acc[2][13];
  #pragma unroll
  for (int s = 0; s < 2; s++)
    #pragma unroll
    for (int i = 0; i < 13; i++) acc[s][i] = (f32x4_t){0.f, 0.f, 0.f, 0.f};

  const unsigned short* Wp = W4T + (size_t)slab * NSLAB_ELEMS;
  for (int kc = 0; kc < 4; kc++) {
    bf16x8_t a0 = *reinterpret_cast<const bf16x8_t*>(&xt[(rb + m16) * 136 + kc * 32 + quad * 8]);
    bf16x8_t a1 = *reinterpret_cast<const bf16x8_t*>(&xt[(rb + 16 + m16) * 136 + kc * 32 + quad * 8]);
    #pragma unroll
    for (int i = 0; i < 13; i++) {
      bf16x8_t b = *reinterpret_cast<const bf16x8_t*>(
          &Wp[(size_t)(i * 16 + m16) * KP_NODE + kc * 32 + quad * 8]);
      acc[0][i] = __builtin_amdgcn_mfma_f32_16x16x32_bf16(a0, b, acc[0][i], 0, 0, 0);
      acc[1][i] = __builtin_amdgcn_mfma_f32_16x16x32_bf16(a1, b, acc[1][i], 0, 0, 0);
    }
  }
  __syncthreads();   // x_tile dead; smem becomes staging

  unsigned short* stg  = (unsigned short*)smem;
  float*          stgf = (float*)smem;

  if (slab < 2) {
    // q or k: head-padded [*, 256] bf16, 2 rounds of 64 rows (32 KB staged)
    unsigned short* gb = (slab == 0) ? q_b : k_b;
    for (int h = 0; h < 2; h++) {
      for (int idx = tid; idx < 896; idx += 256) {     // zero pads: 64 rows * 14 us4
        int r = idx / 14, j = idx % 14;
        int col = (j < 7) ? (100 + j * 4) : (228 + (j - 7) * 4);
        us4 z = {0, 0, 0, 0};
        *reinterpret_cast<us4*>(&stg[r * 256 + col]) = z;
      }
      if ((wave >> 1) == h) {
        int rl = (wave & 1) * 32 + quad * 4;
        for (int s = 0; s < 2; s++)
          #pragma unroll
          for (int i = 0; i < 13; i++) {
            int c = i * 16 + m16;
            if (c < 200) {
              int pc = (c < 100) ? c : c + 28;
              #pragma unroll
              for (int r = 0; r < 4; r++)
                stg[(rl + s * 16 + r) * 256 + pc] = f2b(acc[s][i][r] + bias_v[i]);
            }
          }
      }
      __syncthreads();
      const int rh = nrows - h * 64;
      uint4* g = (uint4*)(gb + (size_t)(n0 + h * 64) * PAD_HC);
      for (int idx = tid; idx < 2048; idx += 256)      // 64 rows * 32 uint4
        if ((idx >> 5) < rh) g[idx] = ((const uint4*)stg)[idx];
      __syncthreads();
    }
  } else if (slab == 2) {
    // v: compact [*, 200] bf16, 2 rounds of 64 rows (25.6 KB staged)
    for (int h = 0; h < 2; h++) {
      if ((wave >> 1) == h) {
        int rl = (wave & 1) * 32 + quad * 4;
        for (int s = 0; s < 2; s++)
          #pragma unroll
          for (int i = 0; i < 13; i++) {
            int c = i * 16 + m16;
            if (c < 200) {
              #pragma unroll
              for (int r = 0; r < 4; r++)
                stg[(rl + s * 16 + r) * 200 + c] = f2b(acc[s][i][r] + bias_v[i]);
            }
          }
      }
      __syncthreads();
      const int rh = nrows - h * 64;
      uint4* g = (uint4*)(v_b + (size_t)(n0 + h * 64) * HC);
      for (int idx = tid; idx < 1600; idx += 256)      // 64 rows * 25 uint4
        if (idx / 25 < rh) g[idx] = ((const uint4*)stg)[idx];
      __syncthreads();
    }
  } else {
    // skip/out: compact [*, 200] fp32, 4 rounds of 32 rows (25.6 KB staged)
    for (int h = 0; h < 4; h++) {
      if (wave == h) {
        int rl = quad * 4;
        for (int s = 0; s < 2; s++)
          #pragma unroll
          for (int i = 0; i < 13; i++) {
            int c = i * 16 + m16;
            if (c < 200) {
              #pragma unroll
              for (int r = 0; r < 4; r++)
                stgf[(rl + s * 16 + r) * 200 + c] = acc[s][i][r] + bias_v[i];
            }
          }
      }
      __syncthreads();
      const int rh = nrows - h * 32;
      uint4* g = (uint4*)(out + (size_t)(n0 + h * 32) * HC);
      for (int idx = tid; idx < 1600; idx += 256)      // 32 rows * 50 uint4
        if (idx / 50 < rh) g[idx] = ((const uint4*)stgf)[idx];
      __syncthreads();
    }
  }
}

// ---------------- edge kernel: t_enc -> e = edge_attr@We -> alpha via MFMA diag -> exbuf, v_e
__global__ __launch_bounds__(256) void edge_gemm(
    const int* __restrict__ edge_index, const float* __restrict__ t,
    const float* __restrict__ last_update, const float* __restrict__ msg,
    const float* __restrict__ w_time, const float* __restrict__ b_time,
    const unsigned short* __restrict__ WeT,
    const unsigned short* __restrict__ q_b, const unsigned short* __restrict__ k_b,
    const unsigned short* __restrict__ v_b,
    unsigned short* __restrict__ v_e, float* __restrict__ exbuf)
{
  __shared__ __align__(16) unsigned short e_lds[64 * EW];   // 33 KB, reused ea -> e(padded)
  __shared__ int   src_s[64], dst_s[64];
  __shared__ float rel_s[64], wt_s[TIME_DIM], bt_s[TIME_DIM];

  const int tid = threadIdx.x;
  const int e0 = blockIdx.x * 64;

  if (tid < TIME_DIM) { wt_s[tid] = w_time[tid]; bt_s[tid] = b_time[tid]; }
  else if (tid >= 128 && tid < 192) {
    int el = tid - 128; int e = e0 + el;
    int s = edge_index[e], d = edge_index[N_EDGES + e];
    src_s[el] = s; dst_s[el] = d;
    rel_s[el] = fabsf(last_update[s] - t[e]);
  }
  __syncthreads();

  const int lane = tid & 63, wave = tid >> 6;
  const int m16 = lane & 15, quad = lane >> 4;
  const int r0 = wave * 16;
  unsigned short* my = e_lds + r0 * EW;

  // phase A: stage edge_attr rows r0..r0+15, cols 0..223 = [cos | msg | 0]
  for (int it = 0; it < 14; it++) {            // 16 rows * 56 us4-chunks / 64 lanes
    int idx = it * 64 + lane;
    int row = idx / 56, c4 = (idx % 56) * 4;
    us4 o;
    if (c4 < TIME_DIM) {
      float rel = rel_s[r0 + row];
      o.x = f2b(cosf(rel * wt_s[c4 + 0] + bt_s[c4 + 0]));
      o.y = f2b(cosf(rel * wt_s[c4 + 1] + bt_s[c4 + 1]));
      o.z = f2b(cosf(rel * wt_s[c4 + 2] + bt_s[c4 + 2]));
      o.w = f2b(cosf(rel * wt_s[c4 + 3] + bt_s[c4 + 3]));
    } else if (c4 < EDGE_DIM) {
      float4 m = *reinterpret_cast<const float4*>(
          msg + (size_t)(e0 + r0 + row) * MSG_DIM + (c4 - TIME_DIM));
      o.x = f2b(m.x); o.y = f2b(m.y); o.z = f2b(m.z); o.w = f2b(m.w);
    } else {
      o.x = o.y = o.z = o.w = 0;
    }
    *reinterpret_cast<us4*>(&my[row * EW + c4]) = o;
  }
  __syncthreads();

  // phase B: e = ea @ WeT   (wave's own 16 rows)
  f32x4_t acc[13];
  #pragma unroll
  for (int i = 0; i < 13; i++) acc[i] = (f32x4_t){0.f, 0.f, 0.f, 0.f};

  for (int kc = 0; kc < 7; kc++) {
    bf16x8_t a = *reinterpret_cast<const bf16x8_t*>(&my[m16 * EW + kc * 32 + quad * 8]);
    #pragma unroll
    for (int nt = 0; nt < 13; nt++) {
      bf16x8_t b = *reinterpret_cast<const bf16x8_t*>(
          &WeT[(nt * 16 + m16) * KP_EDGE + kc * 32 + quad * 8]);
      acc[nt] = __builtin_amdgcn_mfma_f32_16x16x32_bf16(a, b, acc[nt], 0, 0, 0);
    }
  }
  __syncthreads();

  // writeback e (bf16) into head-padded layout: col c -> (c<100 ? c : c+28)
  #pragma unroll
  for (int nt = 0; nt < 13; nt++) {
    int c = nt * 16 + m16;
    if (c < 200) {
      int pc = (c < 100) ? c : c + 28;
      #pragma unroll
      for (int r = 0; r < 4; r++)
        my[(quad * 4 + r) * EW + pc] = f2b(acc[nt][r]);
    }
  }
  // zero pads cols 100..127 and 228..255 of own rows
  for (int idx = lane; idx < 224; idx += 64) {  // 16 rows * 14 us4
    int row = idx / 14, j = idx % 14;
    int col = (j < 7) ? (100 + j * 4) : (228 + (j - 7) * 4);
    us4 z = {0, 0, 0, 0};
    *reinterpret_cast<us4*>(&my[row * EW + col]) = z;
  }
  __syncthreads();

  // phase C: alpha via MFMA diagonal.  D[m][n] = q[dst_m] . (k[src_n] + e_n)
  f32x4_t dacc[2];
  dacc[0] = (f32x4_t){0.f, 0.f, 0.f, 0.f};
  dacc[1] = (f32x4_t){0.f, 0.f, 0.f, 0.f};
  const int my_src = src_s[r0 + m16];
  const int my_dst = dst_s[r0 + m16];
  #pragma unroll
  for (int h = 0; h < 2; h++) {
    #pragma unroll
    for (int kc = 0; kc < 4; kc++) {
      int ko = h * 128 + kc * 32 + quad * 8;
      bf16x8_t a  = *reinterpret_cast<const bf16x8_t*>(&q_b[(size_t)my_dst * PAD_HC + ko]);
      bf16x8_t kb = *reinterpret_cast<const bf16x8_t*>(&k_b[(size_t)my_src * PAD_HC + ko]);
      bf16x8_t eb = *reinterpret_cast<const bf16x8_t*>(&my[m16 * EW + ko]);
      dacc[h] = __builtin_amdgcn_mfma_f32_16x16x32_bf16(a, kb, dacc[h], 0, 0, 0);
      dacc[h] = __builtin_amdgcn_mfma_f32_16x16x32_bf16(a, eb, dacc[h], 0, 0, 0);
    }
  }
  if (quad == (m16 >> 2)) {
    int r = m16 & 3;
    int e = e0 + r0 + m16;
    exbuf[(size_t)e * 2 + 0] = expf(dacc[0][r] * 0.1f);
    exbuf[(size_t)e * 2 + 1] = expf(dacc[1][r] * 0.1f);
  }

  // phase D: v_e = v_b[src] + e   (compact 200 cols, bf16)
  for (int idx = lane; idx < 800; idx += 64) {  // 16 rows * 50 us4
    int row = idx / 50, c = (idx % 50) * 4;
    int pc = (c < 100) ? c : c + 28;
    us4 ev = *reinterpret_cast<const us4*>(&my[row * EW + pc]);
    us4 vv = *reinterpret_cast<const us4*>(&v_b[(size_t)src_s[r0 + row] * HC + c]);
    us4 o;
    o.x = f2b(b2f(ev.x) + b2f(vv.x));
    o.y = f2b(b2f(ev.y) + b2f(vv.y));
    o.z = f2b(b2f(ev.z) + b2f(vv.z));
    o.w = f2b(b2f(ev.w) + b2f(vv.w));
    *reinterpret_cast<us4*>(&v_e[(size_t)(e0 + r0 + row) * HC + c]) = o;
  }
}

// ---------------- CSR build ----------------
__global__ __launch_bounds__(256) void hist_kernel(const int* __restrict__ edge_index,
                                                   int* __restrict__ deg)
{
  int e = blockIdx.x * 256 + threadIdx.x;
  if (e < N_EDGES) atomicAdd(&deg[edge_index[N_EDGES + e]], 1);
}

__global__ __launch_bounds__(256) void scan1(const int* __restrict__ deg,
                                             int* __restrict__ cursor, int* __restrict__ bsum)
{
  __shared__ int s[256];
  const int tid = threadIdx.x;
  const int base = blockIdx.x * 1024 + tid * 4;
  int v[4]; int sum = 0;
  #pragma unroll
  for (int j = 0; j < 4; j++) {
    int i = base + j;
    v[j] = (i < N_NODES) ? deg[i] : 0;
    sum += v[j];
  }
  s[tid] = sum; __syncthreads();
  for (int d = 1; d < 256; d <<= 1) {
    int y = (tid >= d) ? s[tid - d] : 0;
    __syncthreads();
    s[tid] += y;
    __syncthreads();
  }
  int excl = s[tid] - sum;
  if (tid == 255) bsum[blockIdx.x] = s[255];
  int run = excl;
  #pragma unroll
  for (int j = 0; j < 4; j++) {
    int i = base + j;
    if (i < N_NODES) cursor[i] = run;
    run += v[j];
  }
}

__global__ void scan2(int* __restrict__ bsum, int nb)
{
  if (threadIdx.x == 0) {
    int acc = 0;
    for (int i = 0; i < nb; i++) { int t = bsum[i]; bsum[i] = acc; acc += t; }
  }
}

__global__ __launch_bounds__(256) void scan3(int* __restrict__ cursor,
                                             const int* __restrict__ bsum)
{
  int i = blockIdx.x * 256 + threadIdx.x;
  if (i < N_NODES) cursor[i] += bsum[i >> 10];
}

__global__ __launch_bounds__(256) void fill_csr(const int* __restrict__ edge_index,
                                                int* __restrict__ cursor, int* __restrict__ csr)
{
  int e = blockIdx.x * 256 + threadIdx.x;
  if (e < N_EDGES) {
    int p = atomicAdd(&cursor[edge_index[N_EDGES + e]], 1);
    csr[p] = e;
  }
}

// ---------------- gather: out[n] = skip + sum_e attn * v_e  (one wave per node) --------
__global__ __launch_bounds__(256) void gather_out(
    const int* __restrict__ cursor /* = end offsets after fill */,
    const int* __restrict__ deg, const int* __restrict__ csr,
    const unsigned short* __restrict__ v_e, const float* __restrict__ exbuf,
    float* __restrict__ out)
{
  const int wave = threadIdx.x >> 6, lane = threadIdx.x & 63;
  const int n = blockIdx.x * 4 + wave;
  const int dg = deg[n];
  const int off = cursor[n] - dg;          // start offset (fill advanced cursor by dg)

  float d0 = 1e-16f, d1 = 1e-16f;
  for (int j = 0; j < dg; j++) {
    int e = csr[off + j];
    d0 += exbuf[(size_t)e * 2 + 0];
    d1 += exbuf[(size_t)e * 2 + 1];
  }
  const float i0 = 1.f / d0, i1 = 1.f / d1;

  const int c0 = lane, c1 = lane + 64, c2 = lane + 128, c3 = lane + 192;
  float a0 = 0.f, a1 = 0.f, a2 = 0.f, a3 = 0.f;
  for (int j = 0; j < dg; j++) {
    int e = csr[off + j];
    float w0 = exbuf[(size_t)e * 2 + 0] * i0;
    float w1 = exbuf[(size_t)e * 2 + 1] * i1;
    const unsigned short* vr = v_e + (size_t)e * HC;
    a0 += ((c0 < 100) ? w0 : w1) * b2f(vr[c0]);
    a1 += ((c1 < 100) ? w0 : w1) * b2f(vr[c1]);
    a2 += w1 * b2f(vr[c2]);
    if (c3 < HC) a3 += w1 * b2f(vr[c3]);
  }
  float* o = out + (size_t)n * HC;
  o[c0] += a0; o[c1] += a1; o[c2] += a2;
  if (c3 < HC) o[c3] += a3;
}

// ---------------- launch ----------------
extern "C" void kernel_launch(void* const* d_in, const int* in_sizes, int n_in,
                              void* d_out, int out_size, void* d_ws, size_t ws_size,
                              hipStream_t stream)
{
  const float* x           = (const float*)d_in[0];
  const float* last_update = (const float*)d_in[1];
  const int*   edge_index  = (const int*)  d_in[2];
  const float* t           = (const float*)d_in[3];
  const float* msg         = (const float*)d_in[4];
  const float* w_time      = (const float*)d_in[5];
  const float* b_time      = (const float*)d_in[6];
  const float* Wq = (const float*)d_in[7];  const float* bq = (const float*)d_in[8];
  const float* Wk = (const float*)d_in[9];  const float* bk = (const float*)d_in[10];
  const float* Wv = (const float*)d_in[11]; const float* bv = (const float*)d_in[12];
  const float* We = (const float*)d_in[13];
  const float* Ws = (const float*)d_in[14]; const float* bs = (const float*)d_in[15];
  float* out = (float*)d_out;

  char* ws = (char*)d_ws;
  size_t off = 0;
  auto alloc = [&](size_t bytes) -> void* {
    void* p = ws + off;
    off = (off + bytes + 255) & ~(size_t)255;
    return p;
  };
  unsigned short* W4T   = (unsigned short*)alloc((size_t)W4T_ELEMS * 2);
  unsigned short* WeT   = (unsigned short*)alloc((size_t)NP_EDGE * KP_EDGE * 2);
  float*          bias4 = (float*)         alloc((size_t)4 * 208 * 4);
  unsigned short* q_b   = (unsigned short*)alloc((size_t)N_NODES * PAD_HC * 2);
  unsigned short* k_b   = (unsigned short*)alloc((size_t)N_NODES * PAD_HC * 2);
  unsigned short* v_b   = (unsigned short*)alloc((size_t)N_NODES * HC * 2);
  unsigned short* v_e   = (unsigned short*)alloc((size_t)N_EDGES * HC * 2);
  float*          exbuf = (float*)         alloc((size_t)N_EDGES * 2 * 4);
  int*            deg   = (int*)           alloc((size_t)N_NODES * 4);
  int*            cursor= (int*)           alloc((size_t)N_NODES * 4);
  int*            bsum  = (int*)           alloc((size_t)128 * 4);
  int*            csr   = (int*)           alloc((size_t)N_EDGES * 4);
  // total ws use ~= 310 MB

  hipMemsetAsync(deg, 0, (size_t)N_NODES * 4, stream);

  {
    int total = W4T_ELEMS + NP_EDGE * KP_EDGE + 4 * 208;
    pack_weights<<<(total + 255) / 256, 256, 0, stream>>>(
        Wq, bq, Wk, bk, Wv, bv, We, Ws, bs, W4T, WeT, bias4);
  }
  hist_kernel<<<(N_EDGES + 255) / 256, 256, 0, stream>>>(edge_index, deg);
  const int nb = (N_NODES + 1023) / 1024;   // 98
  scan1<<<nb, 256, 0, stream>>>(deg, cursor, bsum);
  scan2<<<1, 64, 0, stream>>>(bsum, nb);
  scan3<<<(N_NODES + 255) / 256, 256, 0, stream>>>(cursor, bsum);

  node_gemm<<<NCHUNK * 4, 256, 0, stream>>>(x, W4T, bias4, q_b, k_b, v_b, out);
  edge_gemm<<<N_EDGES / 64, 256, 0, stream>>>(
      edge_index, t, last_update, msg, w_time, b_time, WeT, q_b, k_b, v_b,
      v_e, exbuf);
  fill_csr<<<(N_EDGES + 255) / 256, 256, 0, stream>>>(edge_index, cursor, csr);
  gather_out<<<N_NODES / 4, 256, 0, stream>>>(cursor, deg, csr, v_e, exbuf, out);
}

// Round 3
// 1076.997 us; speedup vs baseline: 1.3468x; 1.0627x over previous
//
#include <hip/hip_runtime.h>
#include <math.h>

// ---------------- problem constants ----------------
#define N_NODES 100000
#define N_EDGES 400000
#define IN_CH   100
#define OUT_CH  100
#define HEADS   2
#define HC      200      // HEADS*OUT_CH
#define TIME_DIM 100
#define MSG_DIM  100
#define EDGE_DIM 200
// padded GEMM dims
#define KP_NODE 128      // IN_CH padded to mult of 32
#define KP_EDGE 224      // EDGE_DIM padded to mult of 32
#define NP_EDGE 208      // HC padded to mult of 16 (13 n-tiles)
#define PAD_HC  256      // q/k rows padded: head h at h*128, cols 100..127/228..255 zero
#define EW      264      // e_lds row stride in bf16 elems (528 B)
// node-gemm slab blocking: 4 slabs (q|k|v|skip) x 13 n-tiles (208 cols), 128-node chunks
#define NSLAB_ELEMS (13 * 16 * KP_NODE)   // 26624 bf16 per slab
#define W4T_ELEMS   (4 * NSLAB_ELEMS)     // 106496
#define M_CHUNK 128
#define NCHUNK  782                        // ceil(100000/128)

typedef __attribute__((ext_vector_type(8))) short bf16x8_t;
typedef __attribute__((ext_vector_type(4))) float f32x4_t;

struct __align__(8) us4 { unsigned short x, y, z, w; };

static __device__ __forceinline__ float b2f(unsigned short u){
  union { float f; unsigned int i; } v; v.i = ((unsigned int)u) << 16; return v.f;
}
static __device__ __forceinline__ unsigned short f2b(float f){
  union { float f; unsigned int i; } v; v.f = f;
  unsigned int x = v.i;
  return (unsigned short)((x + 0x7fffu + ((x >> 16) & 1u)) >> 16);
}

// intra-wave LDS ordering without a barrier (and, critically, without the
// vmcnt(0) drain that __syncthreads() implies on gfx950).
// sched_barrier(0) after the waitcnt pins it in the schedule (guide rule #18).
#define LDS_FENCE() do { \
  asm volatile("s_waitcnt lgkmcnt(0)" ::: "memory"); \
  __builtin_amdgcn_sched_barrier(0); \
} while (0)

// ---------------- pack weights ----------------
// W4T: [slab][tile i][j 0..15][k 0..127] bf16, slab = q|k|v|skip, col = i*16+j (208, top 8 zero)
// bias4: [slab][208] fp32
__global__ __launch_bounds__(256) void pack_weights(
    const float* __restrict__ Wq, const float* __restrict__ bq,
    const float* __restrict__ Wk, const float* __restrict__ bk,
    const float* __restrict__ Wv, const float* __restrict__ bv,
    const float* __restrict__ We, const float* __restrict__ Ws, const float* __restrict__ bs,
    unsigned short* __restrict__ W4T, unsigned short* __restrict__ WeT,
    float* __restrict__ bias4)
{
  int idx = blockIdx.x * 256 + threadIdx.x;
  if (idx < W4T_ELEMS) {
    int row = idx >> 7;          // 0..831 = t*16 + j
    int k   = idx & 127;
    int t = row >> 4, j = row & 15;
    int slab = t / 13, i = t % 13;
    int col = i * 16 + j;        // 0..207
    float v = 0.f;
    if (k < IN_CH && col < HC) {
      const float* W = (slab == 0) ? Wq : (slab == 1) ? Wk : (slab == 2) ? Wv : Ws;
      v = W[k * HC + col];
    }
    W4T[idx] = f2b(v);
    return;
  }
  int j = idx - W4T_ELEMS;
  if (j < NP_EDGE * KP_EDGE) {                 // WeT[n][k]
    int n = j / KP_EDGE, k = j % KP_EDGE;
    float v = 0.f;
    if (n < HC && k < EDGE_DIM) v = We[k * HC + n];
    WeT[j] = f2b(v);
    return;
  }
  j -= NP_EDGE * KP_EDGE;
  if (j < 4 * 208) {
    int slab = j / 208, col = j % 208;
    const float* B = (slab == 0) ? bq : (slab == 1) ? bk : (slab == 2) ? bv : bs;
    bias4[j] = (col < HC) ? B[col] : 0.f;
  }
}

// ---------------- node GEMM: 128-node chunk x one 208-col slab per block ----------------
// blockIdx = chunk*4 + slab; 4 waves each own 32 rows.  Fully wave-private:
// each wave stages its own 32 x-rows, computes, and uses its own 8.7 KB slice
// of smem for the epilogue -> ZERO barriers (only intra-wave lgkmcnt fences).
__global__ __launch_bounds__(256) void node_gemm(
    const float* __restrict__ x, const unsigned short* __restrict__ W4T,
    const float* __restrict__ bias4,
    unsigned short* __restrict__ q_b, unsigned short* __restrict__ k_b,
    unsigned short* __restrict__ v_b, float* __restrict__ out)
{
  __shared__ __align__(16) unsigned char smem[34816];  // xt[128][136] bf16, per-wave reuse
  unsigned short* xt = (unsigned short*)smem;

  const int tid   = threadIdx.x;
  const int slab  = blockIdx.x & 3;
  const int chunk = blockIdx.x >> 2;
  const int n0    = chunk * M_CHUNK;
  const int nrows = (N_NODES - n0 < M_CHUNK) ? (N_NODES - n0) : M_CHUNK;

  const int lane = tid & 63, wave = tid >> 6;
  const int m16 = lane & 15, quad = lane >> 4;
  const int rb = wave * 32;

  // stage OWN 32 x-rows (float4 loads), zero rows >= nrows, zero-pad cols 100..127
  for (int idx = lane; idx < 800; idx += 64) {         // 32 rows * 25 float4
    int r = idx / 25, j = (idx % 25) * 4;
    int gr = rb + r;
    unsigned short* dst = xt + gr * 136 + j;
    if (gr < nrows) {
      float4 xv = *reinterpret_cast<const float4*>(x + (size_t)(n0 + gr) * IN_CH + j);
      dst[0] = f2b(xv.x); dst[1] = f2b(xv.y); dst[2] = f2b(xv.z); dst[3] = f2b(xv.w);
    } else {
      us4 z = {0, 0, 0, 0};
      *reinterpret_cast<us4*>(dst) = z;
    }
  }
  for (int idx = lane; idx < 224; idx += 64) {         // 32 rows * 7 us4 pad
    int r = idx / 7, j = idx % 7;
    us4 z = {0, 0, 0, 0};
    *reinterpret_cast<us4*>(&xt[(rb + r) * 136 + 100 + j * 4]) = z;
  }
  LDS_FENCE();

  float bias_v[13];
  #pragma unroll
  for (int i = 0; i < 13; i++) bias_v[i] = bias4[slab * 208 + i * 16 + m16];

  f32x4_t acc[2][13];
  #pragma unroll
  for (int s = 0; s < 2; s++)
    #pragma unroll
    for (int i = 0; i < 13; i++) acc[s][i] = (f32x4_t){0.f, 0.f, 0.f, 0.f};

  const unsigned short* Wp = W4T + (size_t)slab * NSLAB_ELEMS;
  for (int kc = 0; kc < 4; kc++) {
    bf16x8_t a0 = *reinterpret_cast<const bf16x8_t*>(&xt[(rb + m16) * 136 + kc * 32 + quad * 8]);
    bf16x8_t a1 = *reinterpret_cast<const bf16x8_t*>(&xt[(rb + 16 + m16) * 136 + kc * 32 + quad * 8]);
    #pragma unroll
    for (int i = 0; i < 13; i++) {
      bf16x8_t b = *reinterpret_cast<const bf16x8_t*>(
          &Wp[(size_t)(i * 16 + m16) * KP_NODE + kc * 32 + quad * 8]);
      acc[0][i] = __builtin_amdgcn_mfma_f32_16x16x32_bf16(a0, b, acc[0][i], 0, 0, 0);
      acc[1][i] = __builtin_amdgcn_mfma_f32_16x16x32_bf16(a1, b, acc[1][i], 0, 0, 0);
    }
  }

  // epilogue: per-wave private staging in own xt slice (32*136 shorts = 8704 B)
  unsigned short* stg  = xt + rb * 136;
  float*          stgf = (float*)stg;

  if (slab < 2) {
    // q or k: head-padded [*, 256] bf16, 2 sub-rounds of 16 rows (8 KB each)
    unsigned short* gb = (slab == 0) ? q_b : k_b;
    for (int s = 0; s < 2; s++) {
      LDS_FENCE();
      for (int idx = lane; idx < 224; idx += 64) {     // zero pads: 16 rows * 14 us4
        int r = idx / 14, j = idx % 14;
        int col = (j < 7) ? (100 + j * 4) : (228 + (j - 7) * 4);
        us4 z = {0, 0, 0, 0};
        *reinterpret_cast<us4*>(&stg[r * 256 + col]) = z;
      }
      #pragma unroll
      for (int i = 0; i < 13; i++) {
        int c = i * 16 + m16;
        if (c < 200) {
          int pc = (c < 100) ? c : c + 28;
          #pragma unroll
          for (int r = 0; r < 4; r++)
            stg[(quad * 4 + r) * 256 + pc] = f2b(acc[s][i][r] + bias_v[i]);
        }
      }
      LDS_FENCE();
      const int rbase = rb + s * 16;
      uint4* g = (uint4*)(gb + (size_t)(n0 + rbase) * PAD_HC);
      const uint4* sv = (const uint4*)stg;
      for (int idx = lane; idx < 512; idx += 64)       // 16 rows * 32 uint4
        if (rbase + (idx >> 5) < nrows) g[idx] = sv[idx];
    }
  } else if (slab == 2) {
    // v: compact [*, 200] bf16, 2 sub-rounds of 16 rows (6.4 KB each)
    for (int s = 0; s < 2; s++) {
      LDS_FENCE();
      #pragma unroll
      for (int i = 0; i < 13; i++) {
        int c = i * 16 + m16;
        if (c < 200) {
          #pragma unroll
          for (int r = 0; r < 4; r++)
            stg[(quad * 4 + r) * 200 + c] = f2b(acc[s][i][r] + bias_v[i]);
        }
      }
      LDS_FENCE();
      const int rbase = rb + s * 16;
      uint4* g = (uint4*)(v_b + (size_t)(n0 + rbase) * HC);
      const uint4* sv = (const uint4*)stg;
      for (int idx = lane; idx < 400; idx += 64)       // 16 rows * 25 uint4
        if (rbase + idx / 25 < nrows) g[idx] = sv[idx];
    }
  } else {
    // skip/out: compact [*, 200] fp32, 4 sub-rounds of 8 rows (6.4 KB each)
    for (int r8 = 0; r8 < 4; r8++) {
      const int s = r8 >> 1;
      LDS_FENCE();
      if ((quad >> 1) == (r8 & 1)) {
        int lr = (quad & 1) * 4;
        #pragma unroll
        for (int i = 0; i < 13; i++) {
          int c = i * 16 + m16;
          if (c < 200) {
            #pragma unroll
            for (int r = 0; r < 4; r++)
              stgf[(lr + r) * 200 + c] = acc[s][i][r] + bias_v[i];
          }
        }
      }
      LDS_FENCE();
      const int rbase = rb + r8 * 8;
      uint4* g = (uint4*)(out + (size_t)(n0 + rbase) * HC);
      const uint4* sv = (const uint4*)stgf;
      for (int idx = lane; idx < 400; idx += 64)       // 8 rows * 50 uint4
        if (rbase + idx / 50 < nrows) g[idx] = sv[idx];
    }
  }
}

// ---------------- edge kernel: t_enc -> e = edge_attr@We -> alpha via MFMA diag -> exbuf, v_e
// All e_lds rows are wave-private after the initial cross-wave staging, so the
// kernel keeps exactly ONE __syncthreads(); all other phase boundaries are
// intra-wave lgkmcnt fences.  Waves free-run and hide each other's gather latency.
__global__ __launch_bounds__(256) void edge_gemm(
    const int* __restrict__ edge_index, const float* __restrict__ t,
    const float* __restrict__ last_update, const float* __restrict__ msg,
    const float* __restrict__ w_time, const float* __restrict__ b_time,
    const unsigned short* __restrict__ WeT,
    const unsigned short* __restrict__ q_b, const unsigned short* __restrict__ k_b,
    const unsigned short* __restrict__ v_b,
    unsigned short* __restrict__ v_e, float* __restrict__ exbuf)
{
  __shared__ __align__(16) unsigned short e_lds[64 * EW];   // 33 KB, reused ea -> e(padded)
  __shared__ int   src_s[64], dst_s[64];
  __shared__ float rel_s[64], wt_s[TIME_DIM], bt_s[TIME_DIM];

  const int tid = threadIdx.x;
  const int e0 = blockIdx.x * 64;

  if (tid < TIME_DIM) { wt_s[tid] = w_time[tid]; bt_s[tid] = b_time[tid]; }
  else if (tid >= 128 && tid < 192) {
    int el = tid - 128; int e = e0 + el;
    int s = edge_index[e], d = edge_index[N_EDGES + e];
    src_s[el] = s; dst_s[el] = d;
    rel_s[el] = fabsf(last_update[s] - t[e]);
  }
  __syncthreads();     // the ONLY barrier: publishes src/dst/rel/wt/bt to all waves

  const int lane = tid & 63, wave = tid >> 6;
  const int m16 = lane & 15, quad = lane >> 4;
  const int r0 = wave * 16;
  unsigned short* my = e_lds + r0 * EW;

  // phase A: stage edge_attr rows r0..r0+15, cols 0..223 = [cos | msg | 0]  (wave-private)
  for (int it = 0; it < 14; it++) {            // 16 rows * 56 us4-chunks / 64 lanes
    int idx = it * 64 + lane;
    int row = idx / 56, c4 = (idx % 56) * 4;
    us4 o;
    if (c4 < TIME_DIM) {
      float rel = rel_s[r0 + row];
      o.x = f2b(cosf(rel * wt_s[c4 + 0] + bt_s[c4 + 0]));
      o.y = f2b(cosf(rel * wt_s[c4 + 1] + bt_s[c4 + 1]));
      o.z = f2b(cosf(rel * wt_s[c4 + 2] + bt_s[c4 + 2]));
      o.w = f2b(cosf(rel * wt_s[c4 + 3] + bt_s[c4 + 3]));
    } else if (c4 < EDGE_DIM) {
      float4 m = *reinterpret_cast<const float4*>(
          msg + (size_t)(e0 + r0 + row) * MSG_DIM + (c4 - TIME_DIM));
      o.x = f2b(m.x); o.y = f2b(m.y); o.z = f2b(m.z); o.w = f2b(m.w);
    } else {
      o.x = o.y = o.z = o.w = 0;
    }
    *reinterpret_cast<us4*>(&my[row * EW + c4]) = o;
  }
  LDS_FENCE();

  // phase B: e = ea @ WeT   (wave's own 16 rows)
  f32x4_t acc[13];
  #pragma unroll
  for (int i = 0; i < 13; i++) acc[i] = (f32x4_t){0.f, 0.f, 0.f, 0.f};

  for (int kc = 0; kc < 7; kc++) {
    bf16x8_t a = *reinterpret_cast<const bf16x8_t*>(&my[m16 * EW + kc * 32 + quad * 8]);
    #pragma unroll
    for (int nt = 0; nt < 13; nt++) {
      bf16x8_t b = *reinterpret_cast<const bf16x8_t*>(
          &WeT[(nt * 16 + m16) * KP_EDGE + kc * 32 + quad * 8]);
      acc[nt] = __builtin_amdgcn_mfma_f32_16x16x32_bf16(a, b, acc[nt], 0, 0, 0);
    }
  }
  LDS_FENCE();

  // writeback e (bf16) into head-padded layout: col c -> (c<100 ? c : c+28)  (own rows)
  #pragma unroll
  for (int nt = 0; nt < 13; nt++) {
    int c = nt * 16 + m16;
    if (c < 200) {
      int pc = (c < 100) ? c : c + 28;
      #pragma unroll
      for (int r = 0; r < 4; r++)
        my[(quad * 4 + r) * EW + pc] = f2b(acc[nt][r]);
    }
  }
  // zero pads cols 100..127 and 228..255 of own rows
  for (int idx = lane; idx < 224; idx += 64) {  // 16 rows * 14 us4
    int row = idx / 14, j = idx % 14;
    int col = (j < 7) ? (100 + j * 4) : (228 + (j - 7) * 4);
    us4 z = {0, 0, 0, 0};
    *reinterpret_cast<us4*>(&my[row * EW + col]) = z;
  }
  LDS_FENCE();

  // phase C: alpha via MFMA diagonal.  D[m][n] = q[dst_m] . (k[src_n] + e_n)
  f32x4_t dacc[2];
  dacc[0] = (f32x4_t){0.f, 0.f, 0.f, 0.f};
  dacc[1] = (f32x4_t){0.f, 0.f, 0.f, 0.f};
  const int my_src = src_s[r0 + m16];
  const int my_dst = dst_s[r0 + m16];
  #pragma unroll
  for (int h = 0; h < 2; h++) {
    #pragma unroll
    for (int kc = 0; kc < 4; kc++) {
      int ko = h * 128 + kc * 32 + quad * 8;
      bf16x8_t a  = *reinterpret_cast<const bf16x8_t*>(&q_b[(size_t)my_dst * PAD_HC + ko]);
      bf16x8_t kb = *reinterpret_cast<const bf16x8_t*>(&k_b[(size_t)my_src * PAD_HC + ko]);
      bf16x8_t eb = *reinterpret_cast<const bf16x8_t*>(&my[m16 * EW + ko]);
      dacc[h] = __builtin_amdgcn_mfma_f32_16x16x32_bf16(a, kb, dacc[h], 0, 0, 0);
      dacc[h] = __builtin_amdgcn_mfma_f32_16x16x32_bf16(a, eb, dacc[h], 0, 0, 0);
    }
  }
  if (quad == (m16 >> 2)) {
    int r = m16 & 3;
    int e = e0 + r0 + m16;
    exbuf[(size_t)e * 2 + 0] = expf(dacc[0][r] * 0.1f);
    exbuf[(size_t)e * 2 + 1] = expf(dacc[1][r] * 0.1f);
  }

  // phase D: v_e = v_b[src] + e   (compact 200 cols, bf16; own rows)
  for (int idx = lane; idx < 800; idx += 64) {  // 16 rows * 50 us4
    int row = idx / 50, c = (idx % 50) * 4;
    int pc = (c < 100) ? c : c + 28;
    us4 ev = *reinterpret_cast<const us4*>(&my[row * EW + pc]);
    us4 vv = *reinterpret_cast<const us4*>(&v_b[(size_t)src_s[r0 + row] * HC + c]);
    us4 o;
    o.x = f2b(b2f(ev.x) + b2f(vv.x));
    o.y = f2b(b2f(ev.y) + b2f(vv.y));
    o.z = f2b(b2f(ev.z) + b2f(vv.z));
    o.w = f2b(b2f(ev.w) + b2f(vv.w));
    *reinterpret_cast<us4*>(&v_e[(size_t)(e0 + r0 + row) * HC + c]) = o;
  }
}

// ---------------- CSR build ----------------
__global__ __launch_bounds__(256) void hist_kernel(const int* __restrict__ edge_index,
                                                   int* __restrict__ deg)
{
  int e = blockIdx.x * 256 + threadIdx.x;
  if (e < N_EDGES) atomicAdd(&deg[edge_index[N_EDGES + e]], 1);
}

__global__ __launch_bounds__(256) void scan1(const int* __restrict__ deg,
                                             int* __restrict__ cursor, int* __restrict__ bsum)
{
  __shared__ int s[256];
  const int tid = threadIdx.x;
  const int base = blockIdx.x * 1024 + tid * 4;
  int v[4]; int sum = 0;
  #pragma unroll
  for (int j = 0; j < 4; j++) {
    int i = base + j;
    v[j] = (i < N_NODES) ? deg[i] : 0;
    sum += v[j];
  }
  s[tid] = sum; __syncthreads();
  for (int d = 1; d < 256; d <<= 1) {
    int y = (tid >= d) ? s[tid - d] : 0;
    __syncthreads();
    s[tid] += y;
    __syncthreads();
  }
  int excl = s[tid] - sum;
  if (tid == 255) bsum[blockIdx.x] = s[255];
  int run = excl;
  #pragma unroll
  for (int j = 0; j < 4; j++) {
    int i = base + j;
    if (i < N_NODES) cursor[i] = run;
    run += v[j];
  }
}

__global__ void scan2(int* __restrict__ bsum, int nb)
{
  if (threadIdx.x == 0) {
    int acc = 0;
    for (int i = 0; i < nb; i++) { int t = bsum[i]; bsum[i] = acc; acc += t; }
  }
}

__global__ __launch_bounds__(256) void scan3(int* __restrict__ cursor,
                                             const int* __restrict__ bsum)
{
  int i = blockIdx.x * 256 + threadIdx.x;
  if (i < N_NODES) cursor[i] += bsum[i >> 10];
}

__global__ __launch_bounds__(256) void fill_csr(const int* __restrict__ edge_index,
                                                int* __restrict__ cursor, int* __restrict__ csr)
{
  int e = blockIdx.x * 256 + threadIdx.x;
  if (e < N_EDGES) {
    int p = atomicAdd(&cursor[edge_index[N_EDGES + e]], 1);
    csr[p] = e;
  }
}

// ---------------- gather: out[n] = skip + sum_e attn * v_e  (one wave per node) --------
__global__ __launch_bounds__(256) void gather_out(
    const int* __restrict__ cursor /* = end offsets after fill */,
    const int* __restrict__ deg, const int* __restrict__ csr,
    const unsigned short* __restrict__ v_e, const float* __restrict__ exbuf,
    float* __restrict__ out)
{
  const int wave = threadIdx.x >> 6, lane = threadIdx.x & 63;
  const int n = blockIdx.x * 4 + wave;
  const int dg = deg[n];
  const int off = cursor[n] - dg;          // start offset (fill advanced cursor by dg)

  float d0 = 1e-16f, d1 = 1e-16f;
  for (int j = 0; j < dg; j++) {
    int e = csr[off + j];
    d0 += exbuf[(size_t)e * 2 + 0];
    d1 += exbuf[(size_t)e * 2 + 1];
  }
  const float i0 = 1.f / d0, i1 = 1.f / d1;

  const int c0 = lane, c1 = lane + 64, c2 = lane + 128, c3 = lane + 192;
  float a0 = 0.f, a1 = 0.f, a2 = 0.f, a3 = 0.f;
  for (int j = 0; j < dg; j++) {
    int e = csr[off + j];
    float w0 = exbuf[(size_t)e * 2 + 0] * i0;
    float w1 = exbuf[(size_t)e * 2 + 1] * i1;
    const unsigned short* vr = v_e + (size_t)e * HC;
    a0 += ((c0 < 100) ? w0 : w1) * b2f(vr[c0]);
    a1 += ((c1 < 100) ? w0 : w1) * b2f(vr[c1]);
    a2 += w1 * b2f(vr[c2]);
    if (c3 < HC) a3 += w1 * b2f(vr[c3]);
  }
  float* o = out + (size_t)n * HC;
  o[c0] += a0; o[c1] += a1; o[c2] += a2;
  if (c3 < HC) o[c3] += a3;
}

// ---------------- launch ----------------
extern "C" void kernel_launch(void* const* d_in, const int* in_sizes, int n_in,
                              void* d_out, int out_size, void* d_ws, size_t ws_size,
                              hipStream_t stream)
{
  const float* x           = (const float*)d_in[0];
  const float* last_update = (const float*)d_in[1];
  const int*   edge_index  = (const int*)  d_in[2];
  const float* t           = (const float*)d_in[3];
  const float* msg         = (const float*)d_in[4];
  const float* w_time      = (const float*)d_in[5];
  const float* b_time      = (const float*)d_in[6];
  const float* Wq = (const float*)d_in[7];  const float* bq = (const float*)d_in[8];
  const float* Wk = (const float*)d_in[9];  const float* bk = (const float*)d_in[10];
  const float* Wv = (const float*)d_in[11]; const float* bv = (const float*)d_in[12];
  const float* We = (const float*)d_in[13];
  const float* Ws = (const float*)d_in[14]; const float* bs = (const float*)d_in[15];
  float* out = (float*)d_out;

  char* ws = (char*)d_ws;
  size_t off = 0;
  auto alloc = [&](size_t bytes) -> void* {
    void* p = ws + off;
    off = (off + bytes + 255) & ~(size_t)255;
    return p;
  };
  unsigned short* W4T   = (unsigned short*)alloc((size_t)W4T_ELEMS * 2);
  unsigned short* WeT   = (unsigned short*)alloc((size_t)NP_EDGE * KP_EDGE * 2);
  float*          bias4 = (float*)         alloc((size_t)4 * 208 * 4);
  unsigned short* q_b   = (unsigned short*)alloc((size_t)N_NODES * PAD_HC * 2);
  unsigned short* k_b   = (unsigned short*)alloc((size_t)N_NODES * PAD_HC * 2);
  unsigned short* v_b   = (unsigned short*)alloc((size_t)N_NODES * HC * 2);
  unsigned short* v_e   = (unsigned short*)alloc((size_t)N_EDGES * HC * 2);
  float*          exbuf = (float*)         alloc((size_t)N_EDGES * 2 * 4);
  int*            deg   = (int*)           alloc((size_t)N_NODES * 4);
  int*            cursor= (int*)           alloc((size_t)N_NODES * 4);
  int*            bsum  = (int*)           alloc((size_t)128 * 4);
  int*            csr   = (int*)           alloc((size_t)N_EDGES * 4);
  // total ws use ~= 310 MB

  hipMemsetAsync(deg, 0, (size_t)N_NODES * 4, stream);

  {
    int total = W4T_ELEMS + NP_EDGE * KP_EDGE + 4 * 208;
    pack_weights<<<(total + 255) / 256, 256, 0, stream>>>(
        Wq, bq, Wk, bk, Wv, bv, We, Ws, bs, W4T, WeT, bias4);
  }
  hist_kernel<<<(N_EDGES + 255) / 256, 256, 0, stream>>>(edge_index, deg);
  const int nb = (N_NODES + 1023) / 1024;   // 98
  scan1<<<nb, 256, 0, stream>>>(deg, cursor, bsum);
  scan2<<<1, 64, 0, stream>>>(bsum, nb);
  scan3<<<(N_NODES + 255) / 256, 256, 0, stream>>>(cursor, bsum);

  node_gemm<<<NCHUNK * 4, 256, 0, stream>>>(x, W4T, bias4, q_b, k_b, v_b, out);
  edge_gemm<<<N_EDGES / 64, 256, 0, stream>>>(
      edge_index, t, last_update, msg, w_time, b_time, WeT, q_b, k_b, v_b,
      v_e, exbuf);
  fill_csr<<<(N_EDGES + 255) / 256, 256, 0, stream>>>(edge_index, cursor, csr);
  gather_out<<<N_NODES / 4, 256, 0, stream>>>(cursor, deg, csr, v_e, exbuf, out);
}

// Round 4
// 1073.796 us; speedup vs baseline: 1.3509x; 1.0030x over previous
//
#include <hip/hip_runtime.h>
#include <math.h>

// ---------------- problem constants ----------------
#define N_NODES 100000
#define N_EDGES 400000
#define IN_CH   100
#define OUT_CH  100
#define HEADS   2
#define HC      200      // HEADS*OUT_CH
#define TIME_DIM 100
#define MSG_DIM  100
#define EDGE_DIM 200
// padded GEMM dims
#define KP_NODE 128      // IN_CH padded to mult of 32
#define KP_EDGE 224      // EDGE_DIM padded to mult of 32
#define NP_EDGE 208      // HC padded to mult of 16 (13 n-tiles)
#define PAD_HC  256      // q/k rows padded: head h at h*128, cols 100..127/228..255 zero
#define EW      264      // e_lds row stride in bf16 elems (528 B)
// node-gemm slab blocking: 4 slabs (q|k|v|skip) x 13 n-tiles (208 cols), 128-node chunks
#define NSLAB_ELEMS (13 * 16 * KP_NODE)   // 26624 bf16 per slab
#define W4T_ELEMS   (4 * NSLAB_ELEMS)     // 106496
#define M_CHUNK 128
#define NCHUNK  782                        // ceil(100000/128)

typedef __attribute__((ext_vector_type(8))) short bf16x8_t;
typedef __attribute__((ext_vector_type(4))) float f32x4_t;

struct __align__(8) us4 { unsigned short x, y, z, w; };

static __device__ __forceinline__ float b2f(unsigned short u){
  union { float f; unsigned int i; } v; v.i = ((unsigned int)u) << 16; return v.f;
}
static __device__ __forceinline__ unsigned short f2b(float f){
  union { float f; unsigned int i; } v; v.f = f;
  unsigned int x = v.i;
  return (unsigned short)((x + 0x7fffu + ((x >> 16) & 1u)) >> 16);
}

// cos via HW: v_cos_f32 takes revolutions; v_fract reduces to [0,1).
// Error ~ |x|*2^-24 rad (<3e-4 here) -- far below the bf16 quantization of edge_attr.
static __device__ __forceinline__ float fast_cos(float x){
  float r = x * 0.15915494309189535f;          // x / (2*pi)
  r = __builtin_amdgcn_fractf(r);              // v_fract_f32
  return __builtin_amdgcn_cosf(r);             // v_cos_f32
}

// intra-wave LDS ordering without a barrier (and, critically, without the
// vmcnt(0) drain that __syncthreads() implies on gfx950).
// sched_barrier(0) after the waitcnt pins it in the schedule (guide rule #18).
#define LDS_FENCE() do { \
  asm volatile("s_waitcnt lgkmcnt(0)" ::: "memory"); \
  __builtin_amdgcn_sched_barrier(0); \
} while (0)

// ---------------- pack weights ----------------
// W4T: [slab][tile i][j 0..15][k 0..127] bf16, slab = q|k|v|skip, col = i*16+j (208, top 8 zero)
// bias4: [slab][208] fp32
__global__ __launch_bounds__(256) void pack_weights(
    const float* __restrict__ Wq, const float* __restrict__ bq,
    const float* __restrict__ Wk, const float* __restrict__ bk,
    const float* __restrict__ Wv, const float* __restrict__ bv,
    const float* __restrict__ We, const float* __restrict__ Ws, const float* __restrict__ bs,
    unsigned short* __restrict__ W4T, unsigned short* __restrict__ WeT,
    float* __restrict__ bias4)
{
  int idx = blockIdx.x * 256 + threadIdx.x;
  if (idx < W4T_ELEMS) {
    int row = idx >> 7;          // 0..831 = t*16 + j
    int k   = idx & 127;
    int t = row >> 4, j = row & 15;
    int slab = t / 13, i = t % 13;
    int col = i * 16 + j;        // 0..207
    float v = 0.f;
    if (k < IN_CH && col < HC) {
      const float* W = (slab == 0) ? Wq : (slab == 1) ? Wk : (slab == 2) ? Wv : Ws;
      v = W[k * HC + col];
    }
    W4T[idx] = f2b(v);
    return;
  }
  int j = idx - W4T_ELEMS;
  if (j < NP_EDGE * KP_EDGE) {                 // WeT[n][k]
    int n = j / KP_EDGE, k = j % KP_EDGE;
    float v = 0.f;
    if (n < HC && k < EDGE_DIM) v = We[k * HC + n];
    WeT[j] = f2b(v);
    return;
  }
  j -= NP_EDGE * KP_EDGE;
  if (j < 4 * 208) {
    int slab = j / 208, col = j % 208;
    const float* B = (slab == 0) ? bq : (slab == 1) ? bk : (slab == 2) ? bv : bs;
    bias4[j] = (col < HC) ? B[col] : 0.f;
  }
}

// ---------------- node GEMM: 128-node chunk x one 208-col slab per block ----------------
// blockIdx = chunk*4 + slab; 4 waves each own 32 rows.  Fully wave-private:
// each wave stages its own 32 x-rows, computes, and uses its own 8.7 KB slice
// of smem for the epilogue -> ZERO barriers (only intra-wave lgkmcnt fences).
__global__ __launch_bounds__(256) void node_gemm(
    const float* __restrict__ x, const unsigned short* __restrict__ W4T,
    const float* __restrict__ bias4,
    unsigned short* __restrict__ q_b, unsigned short* __restrict__ k_b,
    unsigned short* __restrict__ v_b, float* __restrict__ out)
{
  __shared__ __align__(16) unsigned char smem[34816];  // xt[128][136] bf16, per-wave reuse
  unsigned short* xt = (unsigned short*)smem;

  const int tid   = threadIdx.x;
  const int slab  = blockIdx.x & 3;
  const int chunk = blockIdx.x >> 2;
  const int n0    = chunk * M_CHUNK;
  const int nrows = (N_NODES - n0 < M_CHUNK) ? (N_NODES - n0) : M_CHUNK;

  const int lane = tid & 63, wave = tid >> 6;
  const int m16 = lane & 15, quad = lane >> 4;
  const int rb = wave * 32;

  // stage OWN 32 x-rows (float4 loads), zero rows >= nrows, zero-pad cols 100..127
  for (int idx = lane; idx < 800; idx += 64) {         // 32 rows * 25 float4
    int r = idx / 25, j = (idx % 25) * 4;
    int gr = rb + r;
    unsigned short* dst = xt + gr * 136 + j;
    if (gr < nrows) {
      float4 xv = *reinterpret_cast<const float4*>(x + (size_t)(n0 + gr) * IN_CH + j);
      dst[0] = f2b(xv.x); dst[1] = f2b(xv.y); dst[2] = f2b(xv.z); dst[3] = f2b(xv.w);
    } else {
      us4 z = {0, 0, 0, 0};
      *reinterpret_cast<us4*>(dst) = z;
    }
  }
  for (int idx = lane; idx < 224; idx += 64) {         // 32 rows * 7 us4 pad
    int r = idx / 7, j = idx % 7;
    us4 z = {0, 0, 0, 0};
    *reinterpret_cast<us4*>(&xt[(rb + r) * 136 + 100 + j * 4]) = z;
  }
  LDS_FENCE();

  float bias_v[13];
  #pragma unroll
  for (int i = 0; i < 13; i++) bias_v[i] = bias4[slab * 208 + i * 16 + m16];

  f32x4_t acc[2][13];
  #pragma unroll
  for (int s = 0; s < 2; s++)
    #pragma unroll
    for (int i = 0; i < 13; i++) acc[s][i] = (f32x4_t){0.f, 0.f, 0.f, 0.f};

  const unsigned short* Wp = W4T + (size_t)slab * NSLAB_ELEMS;
  for (int kc = 0; kc < 4; kc++) {
    bf16x8_t a0 = *reinterpret_cast<const bf16x8_t*>(&xt[(rb + m16) * 136 + kc * 32 + quad * 8]);
    bf16x8_t a1 = *reinterpret_cast<const bf16x8_t*>(&xt[(rb + 16 + m16) * 136 + kc * 32 + quad * 8]);
    #pragma unroll
    for (int i = 0; i < 13; i++) {
      bf16x8_t b = *reinterpret_cast<const bf16x8_t*>(
          &Wp[(size_t)(i * 16 + m16) * KP_NODE + kc * 32 + quad * 8]);
      acc[0][i] = __builtin_amdgcn_mfma_f32_16x16x32_bf16(a0, b, acc[0][i], 0, 0, 0);
      acc[1][i] = __builtin_amdgcn_mfma_f32_16x16x32_bf16(a1, b, acc[1][i], 0, 0, 0);
    }
  }

  // epilogue: per-wave private staging in own xt slice (32*136 shorts = 8704 B)
  unsigned short* stg  = xt + rb * 136;
  float*          stgf = (float*)stg;

  if (slab < 2) {
    // q or k: head-padded [*, 256] bf16, 2 sub-rounds of 16 rows (8 KB each)
    unsigned short* gb = (slab == 0) ? q_b : k_b;
    for (int s = 0; s < 2; s++) {
      LDS_FENCE();
      for (int idx = lane; idx < 224; idx += 64) {     // zero pads: 16 rows * 14 us4
        int r = idx / 14, j = idx % 14;
        int col = (j < 7) ? (100 + j * 4) : (228 + (j - 7) * 4);
        us4 z = {0, 0, 0, 0};
        *reinterpret_cast<us4*>(&stg[r * 256 + col]) = z;
      }
      #pragma unroll
      for (int i = 0; i < 13; i++) {
        int c = i * 16 + m16;
        if (c < 200) {
          int pc = (c < 100) ? c : c + 28;
          #pragma unroll
          for (int r = 0; r < 4; r++)
            stg[(quad * 4 + r) * 256 + pc] = f2b(acc[s][i][r] + bias_v[i]);
        }
      }
      LDS_FENCE();
      const int rbase = rb + s * 16;
      uint4* g = (uint4*)(gb + (size_t)(n0 + rbase) * PAD_HC);
      const uint4* sv = (const uint4*)stg;
      for (int idx = lane; idx < 512; idx += 64)       // 16 rows * 32 uint4
        if (rbase + (idx >> 5) < nrows) g[idx] = sv[idx];
    }
  } else if (slab == 2) {
    // v: compact [*, 200] bf16, 2 sub-rounds of 16 rows (6.4 KB each)
    for (int s = 0; s < 2; s++) {
      LDS_FENCE();
      #pragma unroll
      for (int i = 0; i < 13; i++) {
        int c = i * 16 + m16;
        if (c < 200) {
          #pragma unroll
          for (int r = 0; r < 4; r++)
            stg[(quad * 4 + r) * 200 + c] = f2b(acc[s][i][r] + bias_v[i]);
        }
      }
      LDS_FENCE();
      const int rbase = rb + s * 16;
      uint4* g = (uint4*)(v_b + (size_t)(n0 + rbase) * HC);
      const uint4* sv = (const uint4*)stg;
      for (int idx = lane; idx < 400; idx += 64)       // 16 rows * 25 uint4
        if (rbase + idx / 25 < nrows) g[idx] = sv[idx];
    }
  } else {
    // skip/out: compact [*, 200] fp32, 4 sub-rounds of 8 rows (6.4 KB each)
    for (int r8 = 0; r8 < 4; r8++) {
      const int s = r8 >> 1;
      LDS_FENCE();
      if ((quad >> 1) == (r8 & 1)) {
        int lr = (quad & 1) * 4;
        #pragma unroll
        for (int i = 0; i < 13; i++) {
          int c = i * 16 + m16;
          if (c < 200) {
            #pragma unroll
            for (int r = 0; r < 4; r++)
              stgf[(lr + r) * 200 + c] = acc[s][i][r] + bias_v[i];
          }
        }
      }
      LDS_FENCE();
      const int rbase = rb + r8 * 8;
      uint4* g = (uint4*)(out + (size_t)(n0 + rbase) * HC);
      const uint4* sv = (const uint4*)stgf;
      for (int idx = lane; idx < 400; idx += 64)       // 8 rows * 50 uint4
        if (rbase + idx / 50 < nrows) g[idx] = sv[idx];
    }
  }
}

// ---------------- edge kernel: t_enc -> e = edge_attr@We -> alpha via MFMA diag -> exbuf, v_e
// One barrier total.  k-fragments preloaded right after the barrier (latency hidden
// under phase A+B); q-fragments preloaded under the e-writeback.  cos via HW v_cos.
// launch_bounds(256,4): LDS caps at 4 blocks/CU anyway -> VGPR budget 128 for free.
__global__ __launch_bounds__(256, 4) void edge_gemm(
    const int* __restrict__ edge_index, const float* __restrict__ t,
    const float* __restrict__ last_update, const float* __restrict__ msg,
    const float* __restrict__ w_time, const float* __restrict__ b_time,
    const unsigned short* __restrict__ WeT,
    const unsigned short* __restrict__ q_b, const unsigned short* __restrict__ k_b,
    const unsigned short* __restrict__ v_b,
    unsigned short* __restrict__ v_e, float* __restrict__ exbuf)
{
  __shared__ __align__(16) unsigned short e_lds[64 * EW];   // 33 KB, reused ea -> e(padded)
  __shared__ int   src_s[64], dst_s[64];
  __shared__ float rel_s[64], wt_s[TIME_DIM], bt_s[TIME_DIM];

  const int tid = threadIdx.x;
  const int e0 = blockIdx.x * 64;

  if (tid < TIME_DIM) { wt_s[tid] = w_time[tid]; bt_s[tid] = b_time[tid]; }
  else if (tid >= 128 && tid < 192) {
    int el = tid - 128; int e = e0 + el;
    int s = edge_index[e], d = edge_index[N_EDGES + e];
    src_s[el] = s; dst_s[el] = d;
    rel_s[el] = fabsf(last_update[s] - t[e]);
  }
  __syncthreads();     // the ONLY barrier: publishes src/dst/rel/wt/bt to all waves

  const int lane = tid & 63, wave = tid >> 6;
  const int m16 = lane & 15, quad = lane >> 4;
  const int r0 = wave * 16;
  unsigned short* my = e_lds + r0 * EW;

  // preload k-fragments for phase C NOW -- their ~600cy gather latency hides
  // under all of phase A (cos) and phase B (MFMA).  8 x 16B = 32 VGPRs.
  const int my_src = src_s[r0 + m16];
  const int my_dst = dst_s[r0 + m16];
  bf16x8_t kpre[2][4];
  #pragma unroll
  for (int h = 0; h < 2; h++)
    #pragma unroll
    for (int kc = 0; kc < 4; kc++)
      kpre[h][kc] = *reinterpret_cast<const bf16x8_t*>(
          &k_b[(size_t)my_src * PAD_HC + h * 128 + kc * 32 + quad * 8]);

  // phase A: stage edge_attr rows r0..r0+15, cols 0..223 = [cos | msg | 0]  (wave-private)
  for (int it = 0; it < 14; it++) {            // 16 rows * 56 us4-chunks / 64 lanes
    int idx = it * 64 + lane;
    int row = idx / 56, c4 = (idx % 56) * 4;
    us4 o;
    if (c4 < TIME_DIM) {
      float rel = rel_s[r0 + row];
      o.x = f2b(fast_cos(rel * wt_s[c4 + 0] + bt_s[c4 + 0]));
      o.y = f2b(fast_cos(rel * wt_s[c4 + 1] + bt_s[c4 + 1]));
      o.z = f2b(fast_cos(rel * wt_s[c4 + 2] + bt_s[c4 + 2]));
      o.w = f2b(fast_cos(rel * wt_s[c4 + 3] + bt_s[c4 + 3]));
    } else if (c4 < EDGE_DIM) {
      float4 m = *reinterpret_cast<const float4*>(
          msg + (size_t)(e0 + r0 + row) * MSG_DIM + (c4 - TIME_DIM));
      o.x = f2b(m.x); o.y = f2b(m.y); o.z = f2b(m.z); o.w = f2b(m.w);
    } else {
      o.x = o.y = o.z = o.w = 0;
    }
    *reinterpret_cast<us4*>(&my[row * EW + c4]) = o;
  }
  LDS_FENCE();

  // phase B: e = ea @ WeT   (wave's own 16 rows)
  f32x4_t acc[13];
  #pragma unroll
  for (int i = 0; i < 13; i++) acc[i] = (f32x4_t){0.f, 0.f, 0.f, 0.f};

  for (int kc = 0; kc < 7; kc++) {
    bf16x8_t a = *reinterpret_cast<const bf16x8_t*>(&my[m16 * EW + kc * 32 + quad * 8]);
    #pragma unroll
    for (int nt = 0; nt < 13; nt++) {
      bf16x8_t b = *reinterpret_cast<const bf16x8_t*>(
          &WeT[(nt * 16 + m16) * KP_EDGE + kc * 32 + quad * 8]);
      acc[nt] = __builtin_amdgcn_mfma_f32_16x16x32_bf16(a, b, acc[nt], 0, 0, 0);
    }
  }
  LDS_FENCE();

  // preload q-fragments -- latency hides under the e-writeback + pad zeroing below.
  bf16x8_t qpre[2][4];
  #pragma unroll
  for (int h = 0; h < 2; h++)
    #pragma unroll
    for (int kc = 0; kc < 4; kc++)
      qpre[h][kc] = *reinterpret_cast<const bf16x8_t*>(
          &q_b[(size_t)my_dst * PAD_HC + h * 128 + kc * 32 + quad * 8]);

  // writeback e (bf16) into head-padded layout: col c -> (c<100 ? c : c+28)  (own rows)
  #pragma unroll
  for (int nt = 0; nt < 13; nt++) {
    int c = nt * 16 + m16;
    if (c < 200) {
      int pc = (c < 100) ? c : c + 28;
      #pragma unroll
      for (int r = 0; r < 4; r++)
        my[(quad * 4 + r) * EW + pc] = f2b(acc[nt][r]);
    }
  }
  // zero pads cols 100..127 and 228..255 of own rows
  for (int idx = lane; idx < 224; idx += 64) {  // 16 rows * 14 us4
    int row = idx / 14, j = idx % 14;
    int col = (j < 7) ? (100 + j * 4) : (228 + (j - 7) * 4);
    us4 z = {0, 0, 0, 0};
    *reinterpret_cast<us4*>(&my[row * EW + col]) = z;
  }
  LDS_FENCE();

  // phase C: alpha via MFMA diagonal.  D[m][n] = q[dst_m] . (k[src_n] + e_n)
  f32x4_t dacc[2];
  dacc[0] = (f32x4_t){0.f, 0.f, 0.f, 0.f};
  dacc[1] = (f32x4_t){0.f, 0.f, 0.f, 0.f};
  #pragma unroll
  for (int h = 0; h < 2; h++) {
    #pragma unroll
    for (int kc = 0; kc < 4; kc++) {
      int ko = h * 128 + kc * 32 + quad * 8;
      bf16x8_t eb = *reinterpret_cast<const bf16x8_t*>(&my[m16 * EW + ko]);
      dacc[h] = __builtin_amdgcn_mfma_f32_16x16x32_bf16(qpre[h][kc], kpre[h][kc], dacc[h], 0, 0, 0);
      dacc[h] = __builtin_amdgcn_mfma_f32_16x16x32_bf16(qpre[h][kc], eb, dacc[h], 0, 0, 0);
    }
  }
  if (quad == (m16 >> 2)) {
    int r = m16 & 3;
    int e = e0 + r0 + m16;
    exbuf[(size_t)e * 2 + 0] = expf(dacc[0][r] * 0.1f);
    exbuf[(size_t)e * 2 + 1] = expf(dacc[1][r] * 0.1f);
  }

  // phase D: v_e = v_b[src] + e   (compact 200 cols, bf16; own rows)
  for (int idx = lane; idx < 800; idx += 64) {  // 16 rows * 50 us4
    int row = idx / 50, c = (idx % 50) * 4;
    int pc = (c < 100) ? c : c + 28;
    us4 ev = *reinterpret_cast<const us4*>(&my[row * EW + pc]);
    us4 vv = *reinterpret_cast<const us4*>(&v_b[(size_t)src_s[r0 + row] * HC + c]);
    us4 o;
    o.x = f2b(b2f(ev.x) + b2f(vv.x));
    o.y = f2b(b2f(ev.y) + b2f(vv.y));
    o.z = f2b(b2f(ev.z) + b2f(vv.z));
    o.w = f2b(b2f(ev.w) + b2f(vv.w));
    *reinterpret_cast<us4*>(&v_e[(size_t)(e0 + r0 + row) * HC + c]) = o;
  }
}

// ---------------- CSR build ----------------
__global__ __launch_bounds__(256) void hist_kernel(const int* __restrict__ edge_index,
                                                   int* __restrict__ deg)
{
  int e = blockIdx.x * 256 + threadIdx.x;
  if (e < N_EDGES) atomicAdd(&deg[edge_index[N_EDGES + e]], 1);
}

__global__ __launch_bounds__(256) void scan1(const int* __restrict__ deg,
                                             int* __restrict__ cursor, int* __restrict__ bsum)
{
  __shared__ int s[256];
  const int tid = threadIdx.x;
  const int base = blockIdx.x * 1024 + tid * 4;
  int v[4]; int sum = 0;
  #pragma unroll
  for (int j = 0; j < 4; j++) {
    int i = base + j;
    v[j] = (i < N_NODES) ? deg[i] : 0;
    sum += v[j];
  }
  s[tid] = sum; __syncthreads();
  for (int d = 1; d < 256; d <<= 1) {
    int y = (tid >= d) ? s[tid - d] : 0;
    __syncthreads();
    s[tid] += y;
    __syncthreads();
  }
  int excl = s[tid] - sum;
  if (tid == 255) bsum[blockIdx.x] = s[255];
  int run = excl;
  #pragma unroll
  for (int j = 0; j < 4; j++) {
    int i = base + j;
    if (i < N_NODES) cursor[i] = run;
    run += v[j];
  }
}

__global__ void scan2(int* __restrict__ bsum, int nb)
{
  if (threadIdx.x == 0) {
    int acc = 0;
    for (int i = 0; i < nb; i++) { int t = bsum[i]; bsum[i] = acc; acc += t; }
  }
}

__global__ __launch_bounds__(256) void scan3(int* __restrict__ cursor,
                                             const int* __restrict__ bsum)
{
  int i = blockIdx.x * 256 + threadIdx.x;
  if (i < N_NODES) cursor[i] += bsum[i >> 10];
}

__global__ __launch_bounds__(256) void fill_csr(const int* __restrict__ edge_index,
                                                int* __restrict__ cursor, int* __restrict__ csr)
{
  int e = blockIdx.x * 256 + threadIdx.x;
  if (e < N_EDGES) {
    int p = atomicAdd(&cursor[edge_index[N_EDGES + e]], 1);
    csr[p] = e;
  }
}

// ---------------- gather: out[n] = skip + sum_e attn * v_e  (one wave per node) --------
__global__ __launch_bounds__(256) void gather_out(
    const int* __restrict__ cursor /* = end offsets after fill */,
    const int* __restrict__ deg, const int* __restrict__ csr,
    const unsigned short* __restrict__ v_e, const float* __restrict__ exbuf,
    float* __restrict__ out)
{
  const int wave = threadIdx.x >> 6, lane = threadIdx.x & 63;
  const int n = blockIdx.x * 4 + wave;
  const int dg = deg[n];
  const int off = cursor[n] - dg;          // start offset (fill advanced cursor by dg)

  float d0 = 1e-16f, d1 = 1e-16f;
  for (int j = 0; j < dg; j++) {
    int e = csr[off + j];
    d0 += exbuf[(size_t)e * 2 + 0];
    d1 += exbuf[(size_t)e * 2 + 1];
  }
  const float i0 = 1.f / d0, i1 = 1.f / d1;

  const int c0 = lane, c1 = lane + 64, c2 = lane + 128, c3 = lane + 192;
  float a0 = 0.f, a1 = 0.f, a2 = 0.f, a3 = 0.f;
  for (int j = 0; j < dg; j++) {
    int e = csr[off + j];
    float w0 = exbuf[(size_t)e * 2 + 0] * i0;
    float w1 = exbuf[(size_t)e * 2 + 1] * i1;
    const unsigned short* vr = v_e + (size_t)e * HC;
    a0 += ((c0 < 100) ? w0 : w1) * b2f(vr[c0]);
    a1 += ((c1 < 100) ? w0 : w1) * b2f(vr[c1]);
    a2 += w1 * b2f(vr[c2]);
    if (c3 < HC) a3 += w1 * b2f(vr[c3]);
  }
  float* o = out + (size_t)n * HC;
  o[c0] += a0; o[c1] += a1; o[c2] += a2;
  if (c3 < HC) o[c3] += a3;
}

// ---------------- launch ----------------
extern "C" void kernel_launch(void* const* d_in, const int* in_sizes, int n_in,
                              void* d_out, int out_size, void* d_ws, size_t ws_size,
                              hipStream_t stream)
{
  const float* x           = (const float*)d_in[0];
  const float* last_update = (const float*)d_in[1];
  const int*   edge_index  = (const int*)  d_in[2];
  const float* t           = (const float*)d_in[3];
  const float* msg         = (const float*)d_in[4];
  const float* w_time      = (const float*)d_in[5];
  const float* b_time      = (const float*)d_in[6];
  const float* Wq = (const float*)d_in[7];  const float* bq = (const float*)d_in[8];
  const float* Wk = (const float*)d_in[9];  const float* bk = (const float*)d_in[10];
  const float* Wv = (const float*)d_in[11]; const float* bv = (const float*)d_in[12];
  const float* We = (const float*)d_in[13];
  const float* Ws = (const float*)d_in[14]; const float* bs = (const float*)d_in[15];
  float* out = (float*)d_out;

  char* ws = (char*)d_ws;
  size_t off = 0;
  auto alloc = [&](size_t bytes) -> void* {
    void* p = ws + off;
    off = (off + bytes + 255) & ~(size_t)255;
    return p;
  };
  unsigned short* W4T   = (unsigned short*)alloc((size_t)W4T_ELEMS * 2);
  unsigned short* WeT   = (unsigned short*)alloc((size_t)NP_EDGE * KP_EDGE * 2);
  float*          bias4 = (float*)         alloc((size_t)4 * 208 * 4);
  unsigned short* q_b   = (unsigned short*)alloc((size_t)N_NODES * PAD_HC * 2);
  unsigned short* k_b   = (unsigned short*)alloc((size_t)N_NODES * PAD_HC * 2);
  unsigned short* v_b   = (unsigned short*)alloc((size_t)N_NODES * HC * 2);
  unsigned short* v_e   = (unsigned short*)alloc((size_t)N_EDGES * HC * 2);
  float*          exbuf = (float*)         alloc((size_t)N_EDGES * 2 * 4);
  int*            deg   = (int*)           alloc((size_t)N_NODES * 4);
  int*            cursor= (int*)           alloc((size_t)N_NODES * 4);
  int*            bsum  = (int*)           alloc((size_t)128 * 4);
  int*            csr   = (int*)           alloc((size_t)N_EDGES * 4);
  // total ws use ~= 310 MB

  hipMemsetAsync(deg, 0, (size_t)N_NODES * 4, stream);

  {
    int total = W4T_ELEMS + NP_EDGE * KP_EDGE + 4 * 208;
    pack_weights<<<(total + 255) / 256, 256, 0, stream>>>(
        Wq, bq, Wk, bk, Wv, bv, We, Ws, bs, W4T, WeT, bias4);
  }
  hist_kernel<<<(N_EDGES + 255) / 256, 256, 0, stream>>>(edge_index, deg);
  const int nb = (N_NODES + 1023) / 1024;   // 98
  scan1<<<nb, 256, 0, stream>>>(deg, cursor, bsum);
  scan2<<<1, 64, 0, stream>>>(bsum, nb);
  scan3<<<(N_NODES + 255) / 256, 256, 0, stream>>>(cursor, bsum);

  node_gemm<<<NCHUNK * 4, 256, 0, stream>>>(x, W4T, bias4, q_b, k_b, v_b, out);
  edge_gemm<<<N_EDGES / 64, 256, 0, stream>>>(
      edge_index, t, last_update, msg, w_time, b_time, WeT, q_b, k_b, v_b,
      v_e, exbuf);
  fill_csr<<<(N_EDGES + 255) / 256, 256, 0, stream>>>(edge_index, cursor, csr);
  gather_out<<<N_NODES / 4, 256, 0, stream>>>(cursor, deg, csr, v_e, exbuf, out);
}

// Round 5
// 917.320 us; speedup vs baseline: 1.5813x; 1.1706x over previous
//
#include <hip/hip_runtime.h>
#include <math.h>

// ---------------- problem constants ----------------
#define N_NODES 100000
#define N_EDGES 400000
#define IN_CH   100
#define OUT_CH  100
#define HEADS   2
#define HC      200      // HEADS*OUT_CH
#define TIME_DIM 100
#define MSG_DIM  100
#define EDGE_DIM 200
// padded GEMM dims
#define KP_NODE 128      // IN_CH padded to mult of 32
#define KP_EDGE 224      // EDGE_DIM padded to mult of 32
#define NP_EDGE 208      // HC padded to mult of 16 (13 n-tiles)
#define PAD_HC  256      // q/k rows padded: head h at h*128, cols 100..127/228..255 zero
#define EW      264      // e_lds row stride in bf16 elems (528 B)
// node-gemm slab blocking: 4 slabs (q|k|v|skip) x 13 n-tiles (208 cols), 128-node chunks
#define NSLAB_ELEMS (13 * 16 * KP_NODE)   // 26624 bf16 per slab
#define W4T_ELEMS   (4 * NSLAB_ELEMS)     // 106496
#define M_CHUNK 128
#define NCHUNK  782                        // ceil(100000/128)

typedef __attribute__((ext_vector_type(8))) short bf16x8_t;
typedef __attribute__((ext_vector_type(4))) float f32x4_t;

struct __align__(8) us4 { unsigned short x, y, z, w; };

static __device__ __forceinline__ float b2f(unsigned short u){
  union { float f; unsigned int i; } v; v.i = ((unsigned int)u) << 16; return v.f;
}
static __device__ __forceinline__ unsigned short f2b(float f){
  union { float f; unsigned int i; } v; v.f = f;
  unsigned int x = v.i;
  return (unsigned short)((x + 0x7fffu + ((x >> 16) & 1u)) >> 16);
}

// cos via HW: v_cos_f32 takes revolutions; v_fract reduces to [0,1).
// Error ~ |x|*2^-24 rad (<3e-4 here) -- far below the bf16 quantization of edge_attr.
static __device__ __forceinline__ float fast_cos(float x){
  float r = x * 0.15915494309189535f;          // x / (2*pi)
  r = __builtin_amdgcn_fractf(r);              // v_fract_f32
  return __builtin_amdgcn_cosf(r);             // v_cos_f32
}

// intra-wave LDS ordering without a barrier (and, critically, without the
// vmcnt(0) drain that __syncthreads() implies on gfx950).
// sched_barrier(0) after the waitcnt pins it in the schedule (guide rule #18).
#define LDS_FENCE() do { \
  asm volatile("s_waitcnt lgkmcnt(0)" ::: "memory"); \
  __builtin_amdgcn_sched_barrier(0); \
} while (0)

// ---------------- pack weights ----------------
// W4T: [slab][tile i][j 0..15][k 0..127] bf16, slab = q|k|v|skip, col = i*16+j (208, top 8 zero)
// bias4: [slab][208] fp32
__global__ __launch_bounds__(256) void pack_weights(
    const float* __restrict__ Wq, const float* __restrict__ bq,
    const float* __restrict__ Wk, const float* __restrict__ bk,
    const float* __restrict__ Wv, const float* __restrict__ bv,
    const float* __restrict__ We, const float* __restrict__ Ws, const float* __restrict__ bs,
    unsigned short* __restrict__ W4T, unsigned short* __restrict__ WeT,
    float* __restrict__ bias4)
{
  int idx = blockIdx.x * 256 + threadIdx.x;
  if (idx < W4T_ELEMS) {
    int row = idx >> 7;          // 0..831 = t*16 + j
    int k   = idx & 127;
    int t = row >> 4, j = row & 15;
    int slab = t / 13, i = t % 13;
    int col = i * 16 + j;        // 0..207
    float v = 0.f;
    if (k < IN_CH && col < HC) {
      const float* W = (slab == 0) ? Wq : (slab == 1) ? Wk : (slab == 2) ? Wv : Ws;
      v = W[k * HC + col];
    }
    W4T[idx] = f2b(v);
    return;
  }
  int j = idx - W4T_ELEMS;
  if (j < NP_EDGE * KP_EDGE) {                 // WeT[n][k]
    int n = j / KP_EDGE, k = j % KP_EDGE;
    float v = 0.f;
    if (n < HC && k < EDGE_DIM) v = We[k * HC + n];
    WeT[j] = f2b(v);
    return;
  }
  j -= NP_EDGE * KP_EDGE;
  if (j < 4 * 208) {
    int slab = j / 208, col = j % 208;
    const float* B = (slab == 0) ? bq : (slab == 1) ? bk : (slab == 2) ? bv : bs;
    bias4[j] = (col < HC) ? B[col] : 0.f;
  }
}

// ---------------- node GEMM: 128-node chunk x one 208-col slab per block ----------------
// blockIdx = chunk*4 + slab; 4 waves each own 32 rows.  Fully wave-private:
// each wave stages its own 32 x-rows, computes, and uses its own 8.7 KB slice
// of smem for the epilogue -> ZERO barriers (only intra-wave lgkmcnt fences).
__global__ __launch_bounds__(256) void node_gemm(
    const float* __restrict__ x, const unsigned short* __restrict__ W4T,
    const float* __restrict__ bias4,
    unsigned short* __restrict__ q_b, unsigned short* __restrict__ k_b,
    unsigned short* __restrict__ v_b, float* __restrict__ out)
{
  __shared__ __align__(16) unsigned char smem[34816];  // xt[128][136] bf16, per-wave reuse
  unsigned short* xt = (unsigned short*)smem;

  const int tid   = threadIdx.x;
  const int slab  = blockIdx.x & 3;
  const int chunk = blockIdx.x >> 2;
  const int n0    = chunk * M_CHUNK;
  const int nrows = (N_NODES - n0 < M_CHUNK) ? (N_NODES - n0) : M_CHUNK;

  const int lane = tid & 63, wave = tid >> 6;
  const int m16 = lane & 15, quad = lane >> 4;
  const int rb = wave * 32;

  // stage OWN 32 x-rows (float4 loads), zero rows >= nrows, zero-pad cols 100..127
  for (int idx = lane; idx < 800; idx += 64) {         // 32 rows * 25 float4
    int r = idx / 25, j = (idx % 25) * 4;
    int gr = rb + r;
    unsigned short* dst = xt + gr * 136 + j;
    if (gr < nrows) {
      float4 xv = *reinterpret_cast<const float4*>(x + (size_t)(n0 + gr) * IN_CH + j);
      dst[0] = f2b(xv.x); dst[1] = f2b(xv.y); dst[2] = f2b(xv.z); dst[3] = f2b(xv.w);
    } else {
      us4 z = {0, 0, 0, 0};
      *reinterpret_cast<us4*>(dst) = z;
    }
  }
  for (int idx = lane; idx < 224; idx += 64) {         // 32 rows * 7 us4 pad
    int r = idx / 7, j = idx % 7;
    us4 z = {0, 0, 0, 0};
    *reinterpret_cast<us4*>(&xt[(rb + r) * 136 + 100 + j * 4]) = z;
  }
  LDS_FENCE();

  float bias_v[13];
  #pragma unroll
  for (int i = 0; i < 13; i++) bias_v[i] = bias4[slab * 208 + i * 16 + m16];

  f32x4_t acc[2][13];
  #pragma unroll
  for (int s = 0; s < 2; s++)
    #pragma unroll
    for (int i = 0; i < 13; i++) acc[s][i] = (f32x4_t){0.f, 0.f, 0.f, 0.f};

  const unsigned short* Wp = W4T + (size_t)slab * NSLAB_ELEMS;
  for (int kc = 0; kc < 4; kc++) {
    bf16x8_t a0 = *reinterpret_cast<const bf16x8_t*>(&xt[(rb + m16) * 136 + kc * 32 + quad * 8]);
    bf16x8_t a1 = *reinterpret_cast<const bf16x8_t*>(&xt[(rb + 16 + m16) * 136 + kc * 32 + quad * 8]);
    #pragma unroll
    for (int i = 0; i < 13; i++) {
      bf16x8_t b = *reinterpret_cast<const bf16x8_t*>(
          &Wp[(size_t)(i * 16 + m16) * KP_NODE + kc * 32 + quad * 8]);
      acc[0][i] = __builtin_amdgcn_mfma_f32_16x16x32_bf16(a0, b, acc[0][i], 0, 0, 0);
      acc[1][i] = __builtin_amdgcn_mfma_f32_16x16x32_bf16(a1, b, acc[1][i], 0, 0, 0);
    }
  }

  // epilogue: per-wave private staging in own xt slice (32*136 shorts = 8704 B)
  unsigned short* stg  = xt + rb * 136;
  float*          stgf = (float*)stg;

  if (slab < 2) {
    // q or k: head-padded [*, 256] bf16, 2 sub-rounds of 16 rows (8 KB each)
    unsigned short* gb = (slab == 0) ? q_b : k_b;
    for (int s = 0; s < 2; s++) {
      LDS_FENCE();
      for (int idx = lane; idx < 224; idx += 64) {     // zero pads: 16 rows * 14 us4
        int r = idx / 14, j = idx % 14;
        int col = (j < 7) ? (100 + j * 4) : (228 + (j - 7) * 4);
        us4 z = {0, 0, 0, 0};
        *reinterpret_cast<us4*>(&stg[r * 256 + col]) = z;
      }
      #pragma unroll
      for (int i = 0; i < 13; i++) {
        int c = i * 16 + m16;
        if (c < 200) {
          int pc = (c < 100) ? c : c + 28;
          #pragma unroll
          for (int r = 0; r < 4; r++)
            stg[(quad * 4 + r) * 256 + pc] = f2b(acc[s][i][r] + bias_v[i]);
        }
      }
      LDS_FENCE();
      const int rbase = rb + s * 16;
      uint4* g = (uint4*)(gb + (size_t)(n0 + rbase) * PAD_HC);
      const uint4* sv = (const uint4*)stg;
      for (int idx = lane; idx < 512; idx += 64)       // 16 rows * 32 uint4
        if (rbase + (idx >> 5) < nrows) g[idx] = sv[idx];
    }
  } else if (slab == 2) {
    // v: compact [*, 200] bf16, 2 sub-rounds of 16 rows (6.4 KB each)
    for (int s = 0; s < 2; s++) {
      LDS_FENCE();
      #pragma unroll
      for (int i = 0; i < 13; i++) {
        int c = i * 16 + m16;
        if (c < 200) {
          #pragma unroll
          for (int r = 0; r < 4; r++)
            stg[(quad * 4 + r) * 200 + c] = f2b(acc[s][i][r] + bias_v[i]);
        }
      }
      LDS_FENCE();
      const int rbase = rb + s * 16;
      uint4* g = (uint4*)(v_b + (size_t)(n0 + rbase) * HC);
      const uint4* sv = (const uint4*)stg;
      for (int idx = lane; idx < 400; idx += 64)       // 16 rows * 25 uint4
        if (rbase + idx / 25 < nrows) g[idx] = sv[idx];
    }
  } else {
    // skip/out: compact [*, 200] fp32, 4 sub-rounds of 8 rows (6.4 KB each)
    for (int r8 = 0; r8 < 4; r8++) {
      const int s = r8 >> 1;
      LDS_FENCE();
      if ((quad >> 1) == (r8 & 1)) {
        int lr = (quad & 1) * 4;
        #pragma unroll
        for (int i = 0; i < 13; i++) {
          int c = i * 16 + m16;
          if (c < 200) {
            #pragma unroll
            for (int r = 0; r < 4; r++)
              stgf[(lr + r) * 200 + c] = acc[s][i][r] + bias_v[i];
          }
        }
      }
      LDS_FENCE();
      const int rbase = rb + r8 * 8;
      uint4* g = (uint4*)(out + (size_t)(n0 + rbase) * HC);
      const uint4* sv = (const uint4*)stgf;
      for (int idx = lane; idx < 400; idx += 64)       // 8 rows * 50 uint4
        if (rbase + idx / 50 < nrows) g[idx] = sv[idx];
    }
  }
}

// ---------------- edge kernel: t_enc -> e = edge_attr@We -> alpha via MFMA diag -> exbuf, v_e
// Phase B is BLOCK-COOPERATIVE: wave w computes n-tiles {w, w+4, w+8, w+12} for ALL
// 64 rows, holding each WeT B-fragment in registers across the 4 m-tiles.  Per-wave
// WeT traffic drops 93KB -> <=23KB (4x fewer scattered L2 lines, the R4 bottleneck).
// k-fragments preloaded early (latency hidden under cos staging + GEMM).
__global__ __launch_bounds__(256, 4) void edge_gemm(
    const int* __restrict__ edge_index, const float* __restrict__ t,
    const float* __restrict__ last_update, const float* __restrict__ msg,
    const float* __restrict__ w_time, const float* __restrict__ b_time,
    const unsigned short* __restrict__ WeT,
    const unsigned short* __restrict__ q_b, const unsigned short* __restrict__ k_b,
    const unsigned short* __restrict__ v_b,
    unsigned short* __restrict__ v_e, float* __restrict__ exbuf)
{
  __shared__ __align__(16) unsigned short e_lds[64 * EW];   // 33 KB, reused ea -> e(padded)
  __shared__ int   src_s[64], dst_s[64];
  __shared__ float rel_s[64], wt_s[TIME_DIM], bt_s[TIME_DIM];

  const int tid = threadIdx.x;
  const int e0 = blockIdx.x * 64;

  if (tid < TIME_DIM) { wt_s[tid] = w_time[tid]; bt_s[tid] = b_time[tid]; }
  else if (tid >= 128 && tid < 192) {
    int el = tid - 128; int e = e0 + el;
    int s = edge_index[e], d = edge_index[N_EDGES + e];
    src_s[el] = s; dst_s[el] = d;
    rel_s[el] = fabsf(last_update[s] - t[e]);
  }
  __syncthreads();     // sync0: publishes src/dst/rel/wt/bt

  const int lane = tid & 63, wave = tid >> 6;
  const int m16 = lane & 15, quad = lane >> 4;
  const int r0 = wave * 16;
  unsigned short* my = e_lds + r0 * EW;

  // preload k-fragments for phase C now -- gather latency hides under phases A+B.
  const int my_src = src_s[r0 + m16];
  const int my_dst = dst_s[r0 + m16];
  bf16x8_t kpre[2][4];
  #pragma unroll
  for (int h = 0; h < 2; h++)
    #pragma unroll
    for (int kc = 0; kc < 4; kc++)
      kpre[h][kc] = *reinterpret_cast<const bf16x8_t*>(
          &k_b[(size_t)my_src * PAD_HC + h * 128 + kc * 32 + quad * 8]);

  // phase A: stage edge_attr rows r0..r0+15, cols 0..223 = [cos | msg | 0]  (own rows)
  for (int it = 0; it < 14; it++) {            // 16 rows * 56 us4-chunks / 64 lanes
    int idx = it * 64 + lane;
    int row = idx / 56, c4 = (idx % 56) * 4;
    us4 o;
    if (c4 < TIME_DIM) {
      float rel = rel_s[r0 + row];
      o.x = f2b(fast_cos(rel * wt_s[c4 + 0] + bt_s[c4 + 0]));
      o.y = f2b(fast_cos(rel * wt_s[c4 + 1] + bt_s[c4 + 1]));
      o.z = f2b(fast_cos(rel * wt_s[c4 + 2] + bt_s[c4 + 2]));
      o.w = f2b(fast_cos(rel * wt_s[c4 + 3] + bt_s[c4 + 3]));
    } else if (c4 < EDGE_DIM) {
      float4 m = *reinterpret_cast<const float4*>(
          msg + (size_t)(e0 + r0 + row) * MSG_DIM + (c4 - TIME_DIM));
      o.x = f2b(m.x); o.y = f2b(m.y); o.z = f2b(m.z); o.w = f2b(m.w);
    } else {
      o.x = o.y = o.z = o.w = 0;
    }
    *reinterpret_cast<us4*>(&my[row * EW + c4]) = o;
  }
  __syncthreads();     // sync1: all 64 edge_attr rows visible to all waves

  // phase B: block-coop e = ea @ WeT.  wave owns nt = wave + 4*i; B-frag held in
  // registers across the 4 m-tiles (4x less WeT traffic).
  f32x4_t acc[4][4];   // [i_own][m_tile]
  #pragma unroll
  for (int i = 0; i < 4; i++)
    #pragma unroll
    for (int m = 0; m < 4; m++) acc[i][m] = (f32x4_t){0.f, 0.f, 0.f, 0.f};

  #pragma unroll
  for (int i = 0; i < 4; i++) {
    const int nt = wave + 4 * i;
    if (nt < 13) {
      for (int kc = 0; kc < 7; kc++) {
        bf16x8_t b = *reinterpret_cast<const bf16x8_t*>(
            &WeT[(nt * 16 + m16) * KP_EDGE + kc * 32 + quad * 8]);
        #pragma unroll
        for (int m = 0; m < 4; m++) {
          bf16x8_t a = *reinterpret_cast<const bf16x8_t*>(
              &e_lds[(m * 16 + m16) * EW + kc * 32 + quad * 8]);
          acc[i][m] = __builtin_amdgcn_mfma_f32_16x16x32_bf16(a, b, acc[i][m], 0, 0, 0);
        }
      }
    }
  }
  __syncthreads();     // sync2: all reads of edge_attr complete before in-place overwrite

  // writeback e (bf16) into head-padded layout: col c -> (c<100 ? c : c+28).
  // wave w writes its nt cols for ALL 64 rows.
  #pragma unroll
  for (int i = 0; i < 4; i++) {
    const int nt = wave + 4 * i;
    if (nt < 13) {
      int c = nt * 16 + m16;
      if (c < 200) {
        int pc = (c < 100) ? c : c + 28;
        #pragma unroll
        for (int m = 0; m < 4; m++)
          #pragma unroll
          for (int r = 0; r < 4; r++)
            e_lds[(m * 16 + quad * 4 + r) * EW + pc] = f2b(acc[i][m][r]);
      }
    }
  }
  // zero pads cols 100..127 and 228..255 of own rows (disjoint bytes from e-writes)
  for (int idx = lane; idx < 224; idx += 64) {  // 16 rows * 14 us4
    int row = idx / 14, j = idx % 14;
    int col = (j < 7) ? (100 + j * 4) : (228 + (j - 7) * 4);
    us4 z = {0, 0, 0, 0};
    *reinterpret_cast<us4*>(&my[row * EW + col]) = z;
  }
  __syncthreads();     // sync3: padded e complete

  // phase C: alpha via MFMA diagonal.  D[m][n] = q[dst_m] . (k[src_n] + e_n)
  f32x4_t dacc[2];
  dacc[0] = (f32x4_t){0.f, 0.f, 0.f, 0.f};
  dacc[1] = (f32x4_t){0.f, 0.f, 0.f, 0.f};
  #pragma unroll
  for (int h = 0; h < 2; h++) {
    #pragma unroll
    for (int kc = 0; kc < 4; kc++) {
      int ko = h * 128 + kc * 32 + quad * 8;
      bf16x8_t a  = *reinterpret_cast<const bf16x8_t*>(&q_b[(size_t)my_dst * PAD_HC + ko]);
      bf16x8_t eb = *reinterpret_cast<const bf16x8_t*>(&my[m16 * EW + ko]);
      dacc[h] = __builtin_amdgcn_mfma_f32_16x16x32_bf16(a, kpre[h][kc], dacc[h], 0, 0, 0);
      dacc[h] = __builtin_amdgcn_mfma_f32_16x16x32_bf16(a, eb, dacc[h], 0, 0, 0);
    }
  }
  if (quad == (m16 >> 2)) {
    int r = m16 & 3;
    int e = e0 + r0 + m16;
    exbuf[(size_t)e * 2 + 0] = expf(dacc[0][r] * 0.1f);
    exbuf[(size_t)e * 2 + 1] = expf(dacc[1][r] * 0.1f);
  }

  // phase D: v_e = v_b[src] + e   (compact 200 cols, bf16; own rows)
  for (int idx = lane; idx < 800; idx += 64) {  // 16 rows * 50 us4
    int row = idx / 50, c = (idx % 50) * 4;
    int pc = (c < 100) ? c : c + 28;
    us4 ev = *reinterpret_cast<const us4*>(&my[row * EW + pc]);
    us4 vv = *reinterpret_cast<const us4*>(&v_b[(size_t)src_s[r0 + row] * HC + c]);
    us4 o;
    o.x = f2b(b2f(ev.x) + b2f(vv.x));
    o.y = f2b(b2f(ev.y) + b2f(vv.y));
    o.z = f2b(b2f(ev.z) + b2f(vv.z));
    o.w = f2b(b2f(ev.w) + b2f(vv.w));
    *reinterpret_cast<us4*>(&v_e[(size_t)(e0 + r0 + row) * HC + c]) = o;
  }
}

// ---------------- CSR build ----------------
__global__ __launch_bounds__(256) void hist_kernel(const int* __restrict__ edge_index,
                                                   int* __restrict__ deg)
{
  int e = blockIdx.x * 256 + threadIdx.x;
  if (e < N_EDGES) atomicAdd(&deg[edge_index[N_EDGES + e]], 1);
}

__global__ __launch_bounds__(256) void scan1(const int* __restrict__ deg,
                                             int* __restrict__ cursor, int* __restrict__ bsum)
{
  __shared__ int s[256];
  const int tid = threadIdx.x;
  const int base = blockIdx.x * 1024 + tid * 4;
  int v[4]; int sum = 0;
  #pragma unroll
  for (int j = 0; j < 4; j++) {
    int i = base + j;
    v[j] = (i < N_NODES) ? deg[i] : 0;
    sum += v[j];
  }
  s[tid] = sum; __syncthreads();
  for (int d = 1; d < 256; d <<= 1) {
    int y = (tid >= d) ? s[tid - d] : 0;
    __syncthreads();
    s[tid] += y;
    __syncthreads();
  }
  int excl = s[tid] - sum;
  if (tid == 255) bsum[blockIdx.x] = s[255];
  int run = excl;
  #pragma unroll
  for (int j = 0; j < 4; j++) {
    int i = base + j;
    if (i < N_NODES) cursor[i] = run;
    run += v[j];
  }
}

__global__ void scan2(int* __restrict__ bsum, int nb)
{
  if (threadIdx.x == 0) {
    int acc = 0;
    for (int i = 0; i < nb; i++) { int t = bsum[i]; bsum[i] = acc; acc += t; }
  }
}

__global__ __launch_bounds__(256) void scan3(int* __restrict__ cursor,
                                             const int* __restrict__ bsum)
{
  int i = blockIdx.x * 256 + threadIdx.x;
  if (i < N_NODES) cursor[i] += bsum[i >> 10];
}

__global__ __launch_bounds__(256) void fill_csr(const int* __restrict__ edge_index,
                                                int* __restrict__ cursor, int* __restrict__ csr)
{
  int e = blockIdx.x * 256 + threadIdx.x;
  if (e < N_EDGES) {
    int p = atomicAdd(&cursor[edge_index[N_EDGES + e]], 1);
    csr[p] = e;
  }
}

// ---------------- gather: out[n] = skip + sum_e attn * v_e  (one wave per node) --------
__global__ __launch_bounds__(256) void gather_out(
    const int* __restrict__ cursor /* = end offsets after fill */,
    const int* __restrict__ deg, const int* __restrict__ csr,
    const unsigned short* __restrict__ v_e, const float* __restrict__ exbuf,
    float* __restrict__ out)
{
  const int wave = threadIdx.x >> 6, lane = threadIdx.x & 63;
  const int n = blockIdx.x * 4 + wave;
  const int dg = deg[n];
  const int off = cursor[n] - dg;          // start offset (fill advanced cursor by dg)

  float d0 = 1e-16f, d1 = 1e-16f;
  for (int j = 0; j < dg; j++) {
    int e = csr[off + j];
    d0 += exbuf[(size_t)e * 2 + 0];
    d1 += exbuf[(size_t)e * 2 + 1];
  }
  const float i0 = 1.f / d0, i1 = 1.f / d1;

  const int c0 = lane, c1 = lane + 64, c2 = lane + 128, c3 = lane + 192;
  float a0 = 0.f, a1 = 0.f, a2 = 0.f, a3 = 0.f;
  for (int j = 0; j < dg; j++) {
    int e = csr[off + j];
    float w0 = exbuf[(size_t)e * 2 + 0] * i0;
    float w1 = exbuf[(size_t)e * 2 + 1] * i1;
    const unsigned short* vr = v_e + (size_t)e * HC;
    a0 += ((c0 < 100) ? w0 : w1) * b2f(vr[c0]);
    a1 += ((c1 < 100) ? w0 : w1) * b2f(vr[c1]);
    a2 += w1 * b2f(vr[c2]);
    if (c3 < HC) a3 += w1 * b2f(vr[c3]);
  }
  float* o = out + (size_t)n * HC;
  o[c0] += a0; o[c1] += a1; o[c2] += a2;
  if (c3 < HC) o[c3] += a3;
}

// ---------------- launch ----------------
extern "C" void kernel_launch(void* const* d_in, const int* in_sizes, int n_in,
                              void* d_out, int out_size, void* d_ws, size_t ws_size,
                              hipStream_t stream)
{
  const float* x           = (const float*)d_in[0];
  const float* last_update = (const float*)d_in[1];
  const int*   edge_index  = (const int*)  d_in[2];
  const float* t           = (const float*)d_in[3];
  const float* msg         = (const float*)d_in[4];
  const float* w_time      = (const float*)d_in[5];
  const float* b_time      = (const float*)d_in[6];
  const float* Wq = (const float*)d_in[7];  const float* bq = (const float*)d_in[8];
  const float* Wk = (const float*)d_in[9];  const float* bk = (const float*)d_in[10];
  const float* Wv = (const float*)d_in[11]; const float* bv = (const float*)d_in[12];
  const float* We = (const float*)d_in[13];
  const float* Ws = (const float*)d_in[14]; const float* bs = (const float*)d_in[15];
  float* out = (float*)d_out;

  char* ws = (char*)d_ws;
  size_t off = 0;
  auto alloc = [&](size_t bytes) -> void* {
    void* p = ws + off;
    off = (off + bytes + 255) & ~(size_t)255;
    return p;
  };
  unsigned short* W4T   = (unsigned short*)alloc((size_t)W4T_ELEMS * 2);
  unsigned short* WeT   = (unsigned short*)alloc((size_t)NP_EDGE * KP_EDGE * 2);
  float*          bias4 = (float*)         alloc((size_t)4 * 208 * 4);
  unsigned short* q_b   = (unsigned short*)alloc((size_t)N_NODES * PAD_HC * 2);
  unsigned short* k_b   = (unsigned short*)alloc((size_t)N_NODES * PAD_HC * 2);
  unsigned short* v_b   = (unsigned short*)alloc((size_t)N_NODES * HC * 2);
  unsigned short* v_e   = (unsigned short*)alloc((size_t)N_EDGES * HC * 2);
  float*          exbuf = (float*)         alloc((size_t)N_EDGES * 2 * 4);
  int*            deg   = (int*)           alloc((size_t)N_NODES * 4);
  int*            cursor= (int*)           alloc((size_t)N_NODES * 4);
  int*            bsum  = (int*)           alloc((size_t)128 * 4);
  int*            csr   = (int*)           alloc((size_t)N_EDGES * 4);
  // total ws use ~= 310 MB

  hipMemsetAsync(deg, 0, (size_t)N_NODES * 4, stream);

  {
    int total = W4T_ELEMS + NP_EDGE * KP_EDGE + 4 * 208;
    pack_weights<<<(total + 255) / 256, 256, 0, stream>>>(
        Wq, bq, Wk, bk, Wv, bv, We, Ws, bs, W4T, WeT, bias4);
  }
  hist_kernel<<<(N_EDGES + 255) / 256, 256, 0, stream>>>(edge_index, deg);
  const int nb = (N_NODES + 1023) / 1024;   // 98
  scan1<<<nb, 256, 0, stream>>>(deg, cursor, bsum);
  scan2<<<1, 64, 0, stream>>>(bsum, nb);
  scan3<<<(N_NODES + 255) / 256, 256, 0, stream>>>(cursor, bsum);

  node_gemm<<<NCHUNK * 4, 256, 0, stream>>>(x, W4T, bias4, q_b, k_b, v_b, out);
  edge_gemm<<<N_EDGES / 64, 256, 0, stream>>>(
      edge_index, t, last_update, msg, w_time, b_time, WeT, q_b, k_b, v_b,
      v_e, exbuf);
  fill_csr<<<(N_EDGES + 255) / 256, 256, 0, stream>>>(edge_index, cursor, csr);
  gather_out<<<N_NODES / 4, 256, 0, stream>>>(cursor, deg, csr, v_e, exbuf, out);
}

// Round 7
// 848.386 us; speedup vs baseline: 1.7098x; 1.0813x over previous
//
#include <hip/hip_runtime.h>
#include <math.h>

// ---------------- problem constants ----------------
#define N_NODES 100000
#define N_EDGES 400000
#define IN_CH   100
#define OUT_CH  100
#define HEADS   2
#define HC      200      // HEADS*OUT_CH
#define TIME_DIM 100
#define MSG_DIM  100
#define EDGE_DIM 200
// padded GEMM dims
#define KP_NODE 128      // IN_CH padded to mult of 32
#define KP_EDGE 224      // EDGE_DIM padded to mult of 32
#define NP_EDGE 208      // HC padded to mult of 16 (13 n-tiles)
#define PAD_HC  256      // q/k rows padded: head h at h*128, cols 100..127/228..255 zero
#define EW      264      // e_lds row stride in bf16 elems (528 B)
// node-gemm slab blocking: 4 slabs (q|k|v|skip) x 13 n-tiles (208 cols), 128-node chunks
#define NSLAB_ELEMS (13 * 16 * KP_NODE)   // 26624 bf16 per slab
#define W4T_ELEMS   (4 * NSLAB_ELEMS)     // 106496
#define M_CHUNK 128
#define NCHUNK  782                        // ceil(100000/128)

typedef __attribute__((ext_vector_type(8))) short bf16x8_t;
typedef __attribute__((ext_vector_type(4))) float f32x4_t;

struct __align__(8) us4 { unsigned short x, y, z, w; };

static __device__ __forceinline__ float b2f(unsigned short u){
  union { float f; unsigned int i; } v; v.i = ((unsigned int)u) << 16; return v.f;
}
static __device__ __forceinline__ unsigned short f2b(float f){
  union { float f; unsigned int i; } v; v.f = f;
  unsigned int x = v.i;
  return (unsigned short)((x + 0x7fffu + ((x >> 16) & 1u)) >> 16);
}

// cos via HW: v_cos_f32 takes revolutions; v_fract reduces to [0,1).
// Error ~ |x|*2^-24 rad (<3e-4 here) -- far below the bf16 quantization of edge_attr.
static __device__ __forceinline__ float fast_cos(float x){
  float r = x * 0.15915494309189535f;          // x / (2*pi)
  r = __builtin_amdgcn_fractf(r);              // v_fract_f32
  return __builtin_amdgcn_cosf(r);             // v_cos_f32
}

// intra-wave LDS ordering without a barrier (and, critically, without the
// vmcnt(0) drain that __syncthreads() implies on gfx950).
// sched_barrier(0) after the waitcnt pins it in the schedule (guide rule #18).
#define LDS_FENCE() do { \
  asm volatile("s_waitcnt lgkmcnt(0)" ::: "memory"); \
  __builtin_amdgcn_sched_barrier(0); \
} while (0)

// ---------------- pack weights ----------------
// W4T: [slab][tile i][j 0..15][k 0..127] bf16, slab = q|k|v|skip, col = i*16+j (208, top 8 zero)
// bias4: [slab][208] fp32
__global__ __launch_bounds__(256) void pack_weights(
    const float* __restrict__ Wq, const float* __restrict__ bq,
    const float* __restrict__ Wk, const float* __restrict__ bk,
    const float* __restrict__ Wv, const float* __restrict__ bv,
    const float* __restrict__ We, const float* __restrict__ Ws, const float* __restrict__ bs,
    unsigned short* __restrict__ W4T, unsigned short* __restrict__ WeT,
    float* __restrict__ bias4)
{
  int idx = blockIdx.x * 256 + threadIdx.x;
  if (idx < W4T_ELEMS) {
    int row = idx >> 7;          // 0..831 = t*16 + j
    int k   = idx & 127;
    int t = row >> 4, j = row & 15;
    int slab = t / 13, i = t % 13;
    int col = i * 16 + j;        // 0..207
    float v = 0.f;
    if (k < IN_CH && col < HC) {
      const float* W = (slab == 0) ? Wq : (slab == 1) ? Wk : (slab == 2) ? Wv : Ws;
      v = W[k * HC + col];
    }
    W4T[idx] = f2b(v);
    return;
  }
  int j = idx - W4T_ELEMS;
  if (j < NP_EDGE * KP_EDGE) {                 // WeT[n][k]
    int n = j / KP_EDGE, k = j % KP_EDGE;
    float v = 0.f;
    if (n < HC && k < EDGE_DIM) v = We[k * HC + n];
    WeT[j] = f2b(v);
    return;
  }
  j -= NP_EDGE * KP_EDGE;
  if (j < 4 * 208) {
    int slab = j / 208, col = j % 208;
    const float* B = (slab == 0) ? bq : (slab == 1) ? bk : (slab == 2) ? bv : bs;
    bias4[j] = (col < HC) ? B[col] : 0.f;
  }
}

// ---------------- node GEMM: 128-node chunk x one 208-col slab per block ----------------
// blockIdx = chunk*4 + slab; 4 waves each own 32 rows.  Fully wave-private:
// each wave stages its own 32 x-rows, computes, and uses its own 8.7 KB slice
// of smem for the epilogue -> ZERO barriers (only intra-wave lgkmcnt fences).
__global__ __launch_bounds__(256) void node_gemm(
    const float* __restrict__ x, const unsigned short* __restrict__ W4T,
    const float* __restrict__ bias4,
    unsigned short* __restrict__ q_b, unsigned short* __restrict__ k_b,
    unsigned short* __restrict__ v_b, float* __restrict__ out)
{
  __shared__ __align__(16) unsigned char smem[34816];  // xt[128][136] bf16, per-wave reuse
  unsigned short* xt = (unsigned short*)smem;

  const int tid   = threadIdx.x;
  const int slab  = blockIdx.x & 3;
  const int chunk = blockIdx.x >> 2;
  const int n0    = chunk * M_CHUNK;
  const int nrows = (N_NODES - n0 < M_CHUNK) ? (N_NODES - n0) : M_CHUNK;

  const int lane = tid & 63, wave = tid >> 6;
  const int m16 = lane & 15, quad = lane >> 4;
  const int rb = wave * 32;

  // stage OWN 32 x-rows (float4 loads), zero rows >= nrows, zero-pad cols 100..127
  for (int idx = lane; idx < 800; idx += 64) {         // 32 rows * 25 float4
    int r = idx / 25, j = (idx % 25) * 4;
    int gr = rb + r;
    unsigned short* dst = xt + gr * 136 + j;
    if (gr < nrows) {
      float4 xv = *reinterpret_cast<const float4*>(x + (size_t)(n0 + gr) * IN_CH + j);
      dst[0] = f2b(xv.x); dst[1] = f2b(xv.y); dst[2] = f2b(xv.z); dst[3] = f2b(xv.w);
    } else {
      us4 z = {0, 0, 0, 0};
      *reinterpret_cast<us4*>(dst) = z;
    }
  }
  for (int idx = lane; idx < 224; idx += 64) {         // 32 rows * 7 us4 pad
    int r = idx / 7, j = idx % 7;
    us4 z = {0, 0, 0, 0};
    *reinterpret_cast<us4*>(&xt[(rb + r) * 136 + 100 + j * 4]) = z;
  }
  LDS_FENCE();

  float bias_v[13];
  #pragma unroll
  for (int i = 0; i < 13; i++) bias_v[i] = bias4[slab * 208 + i * 16 + m16];

  f32x4_t acc[2][13];
  #pragma unroll
  for (int s = 0; s < 2; s++)
    #pragma unroll
    for (int i = 0; i < 13; i++) acc[s][i] = (f32x4_t){0.f, 0.f, 0.f, 0.f};

  const unsigned short* Wp = W4T + (size_t)slab * NSLAB_ELEMS;
  for (int kc = 0; kc < 4; kc++) {
    bf16x8_t a0 = *reinterpret_cast<const bf16x8_t*>(&xt[(rb + m16) * 136 + kc * 32 + quad * 8]);
    bf16x8_t a1 = *reinterpret_cast<const bf16x8_t*>(&xt[(rb + 16 + m16) * 136 + kc * 32 + quad * 8]);
    #pragma unroll
    for (int i = 0; i < 13; i++) {
      bf16x8_t b = *reinterpret_cast<const bf16x8_t*>(
          &Wp[(size_t)(i * 16 + m16) * KP_NODE + kc * 32 + quad * 8]);
      acc[0][i] = __builtin_amdgcn_mfma_f32_16x16x32_bf16(a0, b, acc[0][i], 0, 0, 0);
      acc[1][i] = __builtin_amdgcn_mfma_f32_16x16x32_bf16(a1, b, acc[1][i], 0, 0, 0);
    }
  }

  // epilogue: per-wave private staging in own xt slice (32*136 shorts = 8704 B)
  unsigned short* stg  = xt + rb * 136;
  float*          stgf = (float*)stg;

  if (slab < 2) {
    // q or k: head-padded [*, 256] bf16, 2 sub-rounds of 16 rows (8 KB each)
    unsigned short* gb = (slab == 0) ? q_b : k_b;
    for (int s = 0; s < 2; s++) {
      LDS_FENCE();
      for (int idx = lane; idx < 224; idx += 64) {     // zero pads: 16 rows * 14 us4
        int r = idx / 14, j = idx % 14;
        int col = (j < 7) ? (100 + j * 4) : (228 + (j - 7) * 4);
        us4 z = {0, 0, 0, 0};
        *reinterpret_cast<us4*>(&stg[r * 256 + col]) = z;
      }
      #pragma unroll
      for (int i = 0; i < 13; i++) {
        int c = i * 16 + m16;
        if (c < 200) {
          int pc = (c < 100) ? c : c + 28;
          #pragma unroll
          for (int r = 0; r < 4; r++)
            stg[(quad * 4 + r) * 256 + pc] = f2b(acc[s][i][r] + bias_v[i]);
        }
      }
      LDS_FENCE();
      const int rbase = rb + s * 16;
      uint4* g = (uint4*)(gb + (size_t)(n0 + rbase) * PAD_HC);
      const uint4* sv = (const uint4*)stg;
      for (int idx = lane; idx < 512; idx += 64)       // 16 rows * 32 uint4
        if (rbase + (idx >> 5) < nrows) g[idx] = sv[idx];
    }
  } else if (slab == 2) {
    // v: compact [*, 200] bf16, 2 sub-rounds of 16 rows (6.4 KB each)
    for (int s = 0; s < 2; s++) {
      LDS_FENCE();
      #pragma unroll
      for (int i = 0; i < 13; i++) {
        int c = i * 16 + m16;
        if (c < 200) {
          #pragma unroll
          for (int r = 0; r < 4; r++)
            stg[(quad * 4 + r) * 200 + c] = f2b(acc[s][i][r] + bias_v[i]);
        }
      }
      LDS_FENCE();
      const int rbase = rb + s * 16;
      uint4* g = (uint4*)(v_b + (size_t)(n0 + rbase) * HC);
      const uint4* sv = (const uint4*)stg;
      for (int idx = lane; idx < 400; idx += 64)       // 16 rows * 25 uint4
        if (rbase + idx / 25 < nrows) g[idx] = sv[idx];
    }
  } else {
    // skip/out: compact [*, 200] fp32, 4 sub-rounds of 8 rows (6.4 KB each)
    for (int r8 = 0; r8 < 4; r8++) {
      const int s = r8 >> 1;
      LDS_FENCE();
      if ((quad >> 1) == (r8 & 1)) {
        int lr = (quad & 1) * 4;
        #pragma unroll
        for (int i = 0; i < 13; i++) {
          int c = i * 16 + m16;
          if (c < 200) {
            #pragma unroll
            for (int r = 0; r < 4; r++)
              stgf[(lr + r) * 200 + c] = acc[s][i][r] + bias_v[i];
          }
        }
      }
      LDS_FENCE();
      const int rbase = rb + r8 * 8;
      uint4* g = (uint4*)(out + (size_t)(n0 + rbase) * HC);
      const uint4* sv = (const uint4*)stgf;
      for (int idx = lane; idx < 400; idx += 64)       // 8 rows * 50 uint4
        if (rbase + idx / 50 < nrows) g[idx] = sv[idx];
    }
  }
}

// ---------------- edge kernel ----------------
// Block-cooperative phase B (R5).  NEW: v_e and exbuf are written in CSR-slot
// order (pos[e]) so gather_out streams contiguous rows instead of random ones.
__global__ __launch_bounds__(256, 4) void edge_gemm(
    const int* __restrict__ edge_index, const float* __restrict__ t,
    const float* __restrict__ last_update, const float* __restrict__ msg,
    const float* __restrict__ w_time, const float* __restrict__ b_time,
    const unsigned short* __restrict__ WeT,
    const unsigned short* __restrict__ q_b, const unsigned short* __restrict__ k_b,
    const unsigned short* __restrict__ v_b, const int* __restrict__ pos,
    unsigned short* __restrict__ v_e, float* __restrict__ exbuf)
{
  __shared__ __align__(16) unsigned short e_lds[64 * EW];   // 33 KB, reused ea -> e(padded)
  __shared__ int   src_s[64], dst_s[64], pos_s[64];
  __shared__ float rel_s[64], wt_s[TIME_DIM], bt_s[TIME_DIM];

  const int tid = threadIdx.x;
  const int e0 = blockIdx.x * 64;

  if (tid < TIME_DIM) { wt_s[tid] = w_time[tid]; bt_s[tid] = b_time[tid]; }
  else if (tid >= 128 && tid < 192) {
    int el = tid - 128; int e = e0 + el;
    int s = edge_index[e], d = edge_index[N_EDGES + e];
    src_s[el] = s; dst_s[el] = d;
    pos_s[el] = pos[e];
    rel_s[el] = fabsf(last_update[s] - t[e]);
  }
  __syncthreads();     // sync0: publishes src/dst/pos/rel/wt/bt

  const int lane = tid & 63, wave = tid >> 6;
  const int m16 = lane & 15, quad = lane >> 4;
  const int r0 = wave * 16;
  unsigned short* my = e_lds + r0 * EW;

  // preload k-fragments for phase C now -- gather latency hides under phases A+B.
  const int my_src = src_s[r0 + m16];
  const int my_dst = dst_s[r0 + m16];
  bf16x8_t kpre[2][4];
  #pragma unroll
  for (int h = 0; h < 2; h++)
    #pragma unroll
    for (int kc = 0; kc < 4; kc++)
      kpre[h][kc] = *reinterpret_cast<const bf16x8_t*>(
          &k_b[(size_t)my_src * PAD_HC + h * 128 + kc * 32 + quad * 8]);

  // phase A: stage edge_attr rows r0..r0+15, cols 0..223 = [cos | msg | 0]  (own rows)
  for (int it = 0; it < 14; it++) {            // 16 rows * 56 us4-chunks / 64 lanes
    int idx = it * 64 + lane;
    int row = idx / 56, c4 = (idx % 56) * 4;
    us4 o;
    if (c4 < TIME_DIM) {
      float rel = rel_s[r0 + row];
      o.x = f2b(fast_cos(rel * wt_s[c4 + 0] + bt_s[c4 + 0]));
      o.y = f2b(fast_cos(rel * wt_s[c4 + 1] + bt_s[c4 + 1]));
      o.z = f2b(fast_cos(rel * wt_s[c4 + 2] + bt_s[c4 + 2]));
      o.w = f2b(fast_cos(rel * wt_s[c4 + 3] + bt_s[c4 + 3]));
    } else if (c4 < EDGE_DIM) {
      float4 m = *reinterpret_cast<const float4*>(
          msg + (size_t)(e0 + r0 + row) * MSG_DIM + (c4 - TIME_DIM));
      o.x = f2b(m.x); o.y = f2b(m.y); o.z = f2b(m.z); o.w = f2b(m.w);
    } else {
      o.x = o.y = o.z = o.w = 0;
    }
    *reinterpret_cast<us4*>(&my[row * EW + c4]) = o;
  }
  __syncthreads();     // sync1: all 64 edge_attr rows visible to all waves

  // phase B: block-coop e = ea @ WeT.  wave owns nt = wave + 4*i; B-frag held in
  // registers across the 4 m-tiles (4x less WeT traffic).
  f32x4_t acc[4][4];   // [i_own][m_tile]
  #pragma unroll
  for (int i = 0; i < 4; i++)
    #pragma unroll
    for (int m = 0; m < 4; m++) acc[i][m] = (f32x4_t){0.f, 0.f, 0.f, 0.f};

  #pragma unroll
  for (int i = 0; i < 4; i++) {
    const int nt = wave + 4 * i;
    if (nt < 13) {
      for (int kc = 0; kc < 7; kc++) {
        bf16x8_t b = *reinterpret_cast<const bf16x8_t*>(
            &WeT[(nt * 16 + m16) * KP_EDGE + kc * 32 + quad * 8]);
        #pragma unroll
        for (int m = 0; m < 4; m++) {
          bf16x8_t a = *reinterpret_cast<const bf16x8_t*>(
              &e_lds[(m * 16 + m16) * EW + kc * 32 + quad * 8]);
          acc[i][m] = __builtin_amdgcn_mfma_f32_16x16x32_bf16(a, b, acc[i][m], 0, 0, 0);
        }
      }
    }
  }
  __syncthreads();     // sync2: all reads of edge_attr complete before in-place overwrite

  // writeback e (bf16) into head-padded layout: col c -> (c<100 ? c : c+28).
  // wave w writes its nt cols for ALL 64 rows.
  #pragma unroll
  for (int i = 0; i < 4; i++) {
    const int nt = wave + 4 * i;
    if (nt < 13) {
      int c = nt * 16 + m16;
      if (c < 200) {
        int pc = (c < 100) ? c : c + 28;
        #pragma unroll
        for (int m = 0; m < 4; m++)
          #pragma unroll
          for (int r = 0; r < 4; r++)
            e_lds[(m * 16 + quad * 4 + r) * EW + pc] = f2b(acc[i][m][r]);
      }
    }
  }
  // zero pads cols 100..127 and 228..255 of own rows (disjoint bytes from e-writes)
  for (int idx = lane; idx < 224; idx += 64) {  // 16 rows * 14 us4
    int row = idx / 14, j = idx % 14;
    int col = (j < 7) ? (100 + j * 4) : (228 + (j - 7) * 4);
    us4 z = {0, 0, 0, 0};
    *reinterpret_cast<us4*>(&my[row * EW + col]) = z;
  }
  __syncthreads();     // sync3: padded e complete

  // phase C: alpha via MFMA diagonal.  D[m][n] = q[dst_m] . (k[src_n] + e_n)
  f32x4_t dacc[2];
  dacc[0] = (f32x4_t){0.f, 0.f, 0.f, 0.f};
  dacc[1] = (f32x4_t){0.f, 0.f, 0.f, 0.f};
  #pragma unroll
  for (int h = 0; h < 2; h++) {
    #pragma unroll
    for (int kc = 0; kc < 4; kc++) {
      int ko = h * 128 + kc * 32 + quad * 8;
      bf16x8_t a  = *reinterpret_cast<const bf16x8_t*>(&q_b[(size_t)my_dst * PAD_HC + ko]);
      bf16x8_t eb = *reinterpret_cast<const bf16x8_t*>(&my[m16 * EW + ko]);
      dacc[h] = __builtin_amdgcn_mfma_f32_16x16x32_bf16(a, kpre[h][kc], dacc[h], 0, 0, 0);
      dacc[h] = __builtin_amdgcn_mfma_f32_16x16x32_bf16(a, eb, dacc[h], 0, 0, 0);
    }
  }
  if (quad == (m16 >> 2)) {
    int r = m16 & 3;
    size_t p = (size_t)pos_s[r0 + m16];
    exbuf[p * 2 + 0] = expf(dacc[0][r] * 0.1f);
    exbuf[p * 2 + 1] = expf(dacc[1][r] * 0.1f);
  }

  // phase D: v_e[pos[e]] = v_b[src] + e   (compact 200 cols, bf16; own rows,
  // written at the CSR slot so gather_out streams contiguously)
  for (int idx = lane; idx < 800; idx += 64) {  // 16 rows * 50 us4
    int row = idx / 50, c = (idx % 50) * 4;
    int pc = (c < 100) ? c : c + 28;
    us4 ev = *reinterpret_cast<const us4*>(&my[row * EW + pc]);
    us4 vv = *reinterpret_cast<const us4*>(&v_b[(size_t)src_s[r0 + row] * HC + c]);
    us4 o;
    o.x = f2b(b2f(ev.x) + b2f(vv.x));
    o.y = f2b(b2f(ev.y) + b2f(vv.y));
    o.z = f2b(b2f(ev.z) + b2f(vv.z));
    o.w = f2b(b2f(ev.w) + b2f(vv.w));
    *reinterpret_cast<us4*>(&v_e[(size_t)pos_s[r0 + row] * HC + c]) = o;
  }
}

// ---------------- CSR build ----------------
__global__ __launch_bounds__(256) void hist_kernel(const int* __restrict__ edge_index,
                                                   int* __restrict__ deg)
{
  int e = blockIdx.x * 256 + threadIdx.x;
  if (e < N_EDGES) atomicAdd(&deg[edge_index[N_EDGES + e]], 1);
}

__global__ __launch_bounds__(256) void scan1(const int* __restrict__ deg,
                                             int* __restrict__ cursor, int* __restrict__ bsum)
{
  __shared__ int s[256];
  const int tid = threadIdx.x;
  const int base = blockIdx.x * 1024 + tid * 4;
  int v[4]; int sum = 0;
  #pragma unroll
  for (int j = 0; j < 4; j++) {
    int i = base + j;
    v[j] = (i < N_NODES) ? deg[i] : 0;
    sum += v[j];
  }
  s[tid] = sum; __syncthreads();
  for (int d = 1; d < 256; d <<= 1) {
    int y = (tid >= d) ? s[tid - d] : 0;
    __syncthreads();
    s[tid] += y;
    __syncthreads();
  }
  int excl = s[tid] - sum;
  if (tid == 255) bsum[blockIdx.x] = s[255];
  int run = excl;
  #pragma unroll
  for (int j = 0; j < 4; j++) {
    int i = base + j;
    if (i < N_NODES) cursor[i] = run;
    run += v[j];
  }
}

__global__ void scan2(int* __restrict__ bsum, int nb)
{
  if (threadIdx.x == 0) {
    int acc = 0;
    for (int i = 0; i < nb; i++) { int t = bsum[i]; bsum[i] = acc; acc += t; }
  }
}

__global__ __launch_bounds__(256) void scan3(int* __restrict__ cursor,
                                             const int* __restrict__ bsum)
{
  int i = blockIdx.x * 256 + threadIdx.x;
  if (i < N_NODES) cursor[i] += bsum[i >> 10];
}

// fill: assign each edge its CSR slot (grouped by dst); emits pos[e] only.
__global__ __launch_bounds__(256) void fill_csr(const int* __restrict__ edge_index,
                                                int* __restrict__ cursor, int* __restrict__ pos)
{
  int e = blockIdx.x * 256 + threadIdx.x;
  if (e < N_EDGES) {
    int p = atomicAdd(&cursor[edge_index[N_EDGES + e]], 1);
    pos[e] = p;
  }
}

// ---------------- gather: out[n] = skip + (1/d) * sum_e ex * v_e  ----------------
// v_e/exbuf are in CSR-slot order -> the deg-loop streams a CONTIGUOUS block
// [off*HC, (off+dg)*HC).  Single pass: accumulate unnormalized sums + denominator,
// divide once at the end (same fp32 accumulation as two-pass).
__global__ __launch_bounds__(256) void gather_out(
    const int* __restrict__ cursor /* = end offsets after fill */,
    const int* __restrict__ deg,
    const unsigned short* __restrict__ v_e, const float* __restrict__ exbuf,
    float* __restrict__ out)
{
  const int wave = threadIdx.x >> 6, lane = threadIdx.x & 63;
  const int n = blockIdx.x * 4 + wave;
  const int dg = deg[n];
  const int off = cursor[n] - dg;          // start offset (fill advanced cursor by dg)

  float d0 = 1e-16f, d1 = 1e-16f;
  const int c0 = lane, c1 = lane + 64, c2 = lane + 128, c3 = lane + 192;
  float a0 = 0.f, a1 = 0.f, a2 = 0.f, a3 = 0.f;
  for (int j = 0; j < dg; j++) {
    size_t p = (size_t)(off + j);
    float ex0 = exbuf[p * 2 + 0];
    float ex1 = exbuf[p * 2 + 1];
    d0 += ex0; d1 += ex1;
    const unsigned short* vr = v_e + p * HC;
    a0 += ((c0 < 100) ? ex0 : ex1) * b2f(vr[c0]);
    a1 += ((c1 < 100) ? ex0 : ex1) * b2f(vr[c1]);
    a2 += ex1 * b2f(vr[c2]);
    if (c3 < HC) a3 += ex1 * b2f(vr[c3]);
  }
  const float i0 = 1.f / d0, i1 = 1.f / d1;
  float* o = out + (size_t)n * HC;
  o[c0] += a0 * ((c0 < 100) ? i0 : i1);
  o[c1] += a1 * ((c1 < 100) ? i0 : i1);
  o[c2] += a2 * i1;
  if (c3 < HC) o[c3] += a3 * i1;
}

// ---------------- launch ----------------
extern "C" void kernel_launch(void* const* d_in, const int* in_sizes, int n_in,
                              void* d_out, int out_size, void* d_ws, size_t ws_size,
                              hipStream_t stream)
{
  const float* x           = (const float*)d_in[0];
  const float* last_update = (const float*)d_in[1];
  const int*   edge_index  = (const int*)  d_in[2];
  const float* t           = (const float*)d_in[3];
  const float* msg         = (const float*)d_in[4];
  const float* w_time      = (const float*)d_in[5];
  const float* b_time      = (const float*)d_in[6];
  const float* Wq = (const float*)d_in[7];  const float* bq = (const float*)d_in[8];
  const float* Wk = (const float*)d_in[9];  const float* bk = (const float*)d_in[10];
  const float* Wv = (const float*)d_in[11]; const float* bv = (const float*)d_in[12];
  const float* We = (const float*)d_in[13];
  const float* Ws = (const float*)d_in[14]; const float* bs = (const float*)d_in[15];
  float* out = (float*)d_out;

  char* ws = (char*)d_ws;
  size_t off = 0;
  auto alloc = [&](size_t bytes) -> void* {
    void* p = ws + off;
    off = (off + bytes + 255) & ~(size_t)255;
    return p;
  };
  unsigned short* W4T   = (unsigned short*)alloc((size_t)W4T_ELEMS * 2);
  unsigned short* WeT   = (unsigned short*)alloc((size_t)NP_EDGE * KP_EDGE * 2);
  float*          bias4 = (float*)         alloc((size_t)4 * 208 * 4);
  unsigned short* q_b   = (unsigned short*)alloc((size_t)N_NODES * PAD_HC * 2);
  unsigned short* k_b   = (unsigned short*)alloc((size_t)N_NODES * PAD_HC * 2);
  unsigned short* v_b   = (unsigned short*)alloc((size_t)N_NODES * HC * 2);
  unsigned short* v_e   = (unsigned short*)alloc((size_t)N_EDGES * HC * 2);
  float*          exbuf = (float*)         alloc((size_t)N_EDGES * 2 * 4);
  int*            deg   = (int*)           alloc((size_t)N_NODES * 4);
  int*            cursor= (int*)           alloc((size_t)N_NODES * 4);
  int*            bsum  = (int*)           alloc((size_t)128 * 4);
  int*            pos   = (int*)           alloc((size_t)N_EDGES * 4);
  // total ws use ~= 310 MB

  hipMemsetAsync(deg, 0, (size_t)N_NODES * 4, stream);

  {
    int total = W4T_ELEMS + NP_EDGE * KP_EDGE + 4 * 208;
    pack_weights<<<(total + 255) / 256, 256, 0, stream>>>(
        Wq, bq, Wk, bk, Wv, bv, We, Ws, bs, W4T, WeT, bias4);
  }
  hist_kernel<<<(N_EDGES + 255) / 256, 256, 0, stream>>>(edge_index, deg);
  const int nb = (N_NODES + 1023) / 1024;   // 98
  scan1<<<nb, 256, 0, stream>>>(deg, cursor, bsum);
  scan2<<<1, 64, 0, stream>>>(bsum, nb);
  scan3<<<(N_NODES + 255) / 256, 256, 0, stream>>>(cursor, bsum);
  fill_csr<<<(N_EDGES + 255) / 256, 256, 0, stream>>>(edge_index, cursor, pos);

  node_gemm<<<NCHUNK * 4, 256, 0, stream>>>(x, W4T, bias4, q_b, k_b, v_b, out);
  edge_gemm<<<N_EDGES / 64, 256, 0, stream>>>(
      edge_index, t, last_update, msg, w_time, b_time, WeT, q_b, k_b, v_b, pos,
      v_e, exbuf);
  gather_out<<<N_NODES / 4, 256, 0, stream>>>(cursor, deg, v_e, exbuf, out);
}

// Round 8
// 804.189 us; speedup vs baseline: 1.8037x; 1.0550x over previous
//
#include <hip/hip_runtime.h>
#include <math.h>

// ---------------- problem constants ----------------
#define N_NODES 100000
#define N_EDGES 400000
#define IN_CH   100
#define OUT_CH  100
#define HEADS   2
#define HC      200      // HEADS*OUT_CH
#define TIME_DIM 100
#define MSG_DIM  100
#define EDGE_DIM 200
// padded GEMM dims
#define KP_NODE 128      // IN_CH padded to mult of 32
#define KP_EDGE 224      // EDGE_DIM padded to mult of 32
#define NP_EDGE 208      // HC padded to mult of 16 (13 n-tiles)
#define PAD_HC  256      // q/k rows padded: head h at h*128, cols 100..127/228..255 zero
#define EW      264      // e_lds row stride in bf16 elems (528 B)
// node-gemm slab blocking: 4 slabs (q|k|v|skip) x 13 n-tiles (208 cols), 128-node chunks
#define NSLAB_ELEMS (13 * 16 * KP_NODE)   // 26624 bf16 per slab
#define W4T_ELEMS   (4 * NSLAB_ELEMS)     // 106496
#define M_CHUNK 128
#define NCHUNK  782                        // ceil(100000/128)

typedef __attribute__((ext_vector_type(8))) short bf16x8_t;
typedef __attribute__((ext_vector_type(4))) float f32x4_t;

struct __align__(8) us4 { unsigned short x, y, z, w; };

static __device__ __forceinline__ float b2f(unsigned short u){
  union { float f; unsigned int i; } v; v.i = ((unsigned int)u) << 16; return v.f;
}
static __device__ __forceinline__ unsigned short f2b(float f){
  union { float f; unsigned int i; } v; v.f = f;
  unsigned int x = v.i;
  return (unsigned short)((x + 0x7fffu + ((x >> 16) & 1u)) >> 16);
}

// cos via HW: v_cos_f32 takes revolutions; v_fract reduces to [0,1).
// Error ~ |x|*2^-24 rad (<3e-4 here) -- far below the bf16 quantization of edge_attr.
static __device__ __forceinline__ float fast_cos(float x){
  float r = x * 0.15915494309189535f;          // x / (2*pi)
  r = __builtin_amdgcn_fractf(r);              // v_fract_f32
  return __builtin_amdgcn_cosf(r);             // v_cos_f32
}

// intra-wave LDS ordering without a barrier (and, critically, without the
// vmcnt(0) drain that __syncthreads() implies on gfx950).
// sched_barrier(0) after the waitcnt pins it in the schedule (guide rule #18).
#define LDS_FENCE() do { \
  asm volatile("s_waitcnt lgkmcnt(0)" ::: "memory"); \
  __builtin_amdgcn_sched_barrier(0); \
} while (0)

// ---------------- pack weights ----------------
// W4T: [slab][tile i][j 0..15][k 0..127] bf16, slab = q|k|v|skip, col = i*16+j (208, top 8 zero)
// bias4: [slab][208] fp32
__global__ __launch_bounds__(256) void pack_weights(
    const float* __restrict__ Wq, const float* __restrict__ bq,
    const float* __restrict__ Wk, const float* __restrict__ bk,
    const float* __restrict__ Wv, const float* __restrict__ bv,
    const float* __restrict__ We, const float* __restrict__ Ws, const float* __restrict__ bs,
    unsigned short* __restrict__ W4T, unsigned short* __restrict__ WeT,
    float* __restrict__ bias4)
{
  int idx = blockIdx.x * 256 + threadIdx.x;
  if (idx < W4T_ELEMS) {
    int row = idx >> 7;          // 0..831 = t*16 + j
    int k   = idx & 127;
    int t = row >> 4, j = row & 15;
    int slab = t / 13, i = t % 13;
    int col = i * 16 + j;        // 0..207
    float v = 0.f;
    if (k < IN_CH && col < HC) {
      const float* W = (slab == 0) ? Wq : (slab == 1) ? Wk : (slab == 2) ? Wv : Ws;
      v = W[k * HC + col];
    }
    W4T[idx] = f2b(v);
    return;
  }
  int j = idx - W4T_ELEMS;
  if (j < NP_EDGE * KP_EDGE) {                 // WeT[n][k]
    int n = j / KP_EDGE, k = j % KP_EDGE;
    float v = 0.f;
    if (n < HC && k < EDGE_DIM) v = We[k * HC + n];
    WeT[j] = f2b(v);
    return;
  }
  j -= NP_EDGE * KP_EDGE;
  if (j < 4 * 208) {
    int slab = j / 208, col = j % 208;
    const float* B = (slab == 0) ? bq : (slab == 1) ? bk : (slab == 2) ? bv : bs;
    bias4[j] = (col < HC) ? B[col] : 0.f;
  }
}

// ---------------- node GEMM: 128-node chunk x one 208-col slab per block ----------------
// blockIdx = chunk*4 + slab; 4 waves each own 32 rows.  Fully wave-private:
// each wave stages its own 32 x-rows, computes, and uses its own 8.7 KB slice
// of smem for the epilogue -> ZERO barriers (only intra-wave lgkmcnt fences).
__global__ __launch_bounds__(256) void node_gemm(
    const float* __restrict__ x, const unsigned short* __restrict__ W4T,
    const float* __restrict__ bias4,
    unsigned short* __restrict__ q_b, unsigned short* __restrict__ k_b,
    unsigned short* __restrict__ v_b, float* __restrict__ out)
{
  __shared__ __align__(16) unsigned char smem[34816];  // xt[128][136] bf16, per-wave reuse
  unsigned short* xt = (unsigned short*)smem;

  const int tid   = threadIdx.x;
  const int slab  = blockIdx.x & 3;
  const int chunk = blockIdx.x >> 2;
  const int n0    = chunk * M_CHUNK;
  const int nrows = (N_NODES - n0 < M_CHUNK) ? (N_NODES - n0) : M_CHUNK;

  const int lane = tid & 63, wave = tid >> 6;
  const int m16 = lane & 15, quad = lane >> 4;
  const int rb = wave * 32;

  // stage OWN 32 x-rows (float4 loads), zero rows >= nrows, zero-pad cols 100..127
  for (int idx = lane; idx < 800; idx += 64) {         // 32 rows * 25 float4
    int r = idx / 25, j = (idx % 25) * 4;
    int gr = rb + r;
    unsigned short* dst = xt + gr * 136 + j;
    if (gr < nrows) {
      float4 xv = *reinterpret_cast<const float4*>(x + (size_t)(n0 + gr) * IN_CH + j);
      dst[0] = f2b(xv.x); dst[1] = f2b(xv.y); dst[2] = f2b(xv.z); dst[3] = f2b(xv.w);
    } else {
      us4 z = {0, 0, 0, 0};
      *reinterpret_cast<us4*>(dst) = z;
    }
  }
  for (int idx = lane; idx < 224; idx += 64) {         // 32 rows * 7 us4 pad
    int r = idx / 7, j = idx % 7;
    us4 z = {0, 0, 0, 0};
    *reinterpret_cast<us4*>(&xt[(rb + r) * 136 + 100 + j * 4]) = z;
  }
  LDS_FENCE();

  float bias_v[13];
  #pragma unroll
  for (int i = 0; i < 13; i++) bias_v[i] = bias4[slab * 208 + i * 16 + m16];

  f32x4_t acc[2][13];
  #pragma unroll
  for (int s = 0; s < 2; s++)
    #pragma unroll
    for (int i = 0; i < 13; i++) acc[s][i] = (f32x4_t){0.f, 0.f, 0.f, 0.f};

  const unsigned short* Wp = W4T + (size_t)slab * NSLAB_ELEMS;
  for (int kc = 0; kc < 4; kc++) {
    bf16x8_t a0 = *reinterpret_cast<const bf16x8_t*>(&xt[(rb + m16) * 136 + kc * 32 + quad * 8]);
    bf16x8_t a1 = *reinterpret_cast<const bf16x8_t*>(&xt[(rb + 16 + m16) * 136 + kc * 32 + quad * 8]);
    #pragma unroll
    for (int i = 0; i < 13; i++) {
      bf16x8_t b = *reinterpret_cast<const bf16x8_t*>(
          &Wp[(size_t)(i * 16 + m16) * KP_NODE + kc * 32 + quad * 8]);
      acc[0][i] = __builtin_amdgcn_mfma_f32_16x16x32_bf16(a0, b, acc[0][i], 0, 0, 0);
      acc[1][i] = __builtin_amdgcn_mfma_f32_16x16x32_bf16(a1, b, acc[1][i], 0, 0, 0);
    }
  }

  // epilogue: per-wave private staging in own xt slice (32*136 shorts = 8704 B)
  unsigned short* stg  = xt + rb * 136;
  float*          stgf = (float*)stg;

  if (slab < 2) {
    // q or k: head-padded [*, 256] bf16, 2 sub-rounds of 16 rows (8 KB each)
    unsigned short* gb = (slab == 0) ? q_b : k_b;
    for (int s = 0; s < 2; s++) {
      LDS_FENCE();
      for (int idx = lane; idx < 224; idx += 64) {     // zero pads: 16 rows * 14 us4
        int r = idx / 14, j = idx % 14;
        int col = (j < 7) ? (100 + j * 4) : (228 + (j - 7) * 4);
        us4 z = {0, 0, 0, 0};
        *reinterpret_cast<us4*>(&stg[r * 256 + col]) = z;
      }
      #pragma unroll
      for (int i = 0; i < 13; i++) {
        int c = i * 16 + m16;
        if (c < 200) {
          int pc = (c < 100) ? c : c + 28;
          #pragma unroll
          for (int r = 0; r < 4; r++)
            stg[(quad * 4 + r) * 256 + pc] = f2b(acc[s][i][r] + bias_v[i]);
        }
      }
      LDS_FENCE();
      const int rbase = rb + s * 16;
      uint4* g = (uint4*)(gb + (size_t)(n0 + rbase) * PAD_HC);
      const uint4* sv = (const uint4*)stg;
      for (int idx = lane; idx < 512; idx += 64)       // 16 rows * 32 uint4
        if (rbase + (idx >> 5) < nrows) g[idx] = sv[idx];
    }
  } else if (slab == 2) {
    // v: compact [*, 200] bf16, 2 sub-rounds of 16 rows (6.4 KB each)
    for (int s = 0; s < 2; s++) {
      LDS_FENCE();
      #pragma unroll
      for (int i = 0; i < 13; i++) {
        int c = i * 16 + m16;
        if (c < 200) {
          #pragma unroll
          for (int r = 0; r < 4; r++)
            stg[(quad * 4 + r) * 200 + c] = f2b(acc[s][i][r] + bias_v[i]);
        }
      }
      LDS_FENCE();
      const int rbase = rb + s * 16;
      uint4* g = (uint4*)(v_b + (size_t)(n0 + rbase) * HC);
      const uint4* sv = (const uint4*)stg;
      for (int idx = lane; idx < 400; idx += 64)       // 16 rows * 25 uint4
        if (rbase + idx / 25 < nrows) g[idx] = sv[idx];
    }
  } else {
    // skip/out: compact [*, 200] fp32, 4 sub-rounds of 8 rows (6.4 KB each)
    for (int r8 = 0; r8 < 4; r8++) {
      const int s = r8 >> 1;
      LDS_FENCE();
      if ((quad >> 1) == (r8 & 1)) {
        int lr = (quad & 1) * 4;
        #pragma unroll
        for (int i = 0; i < 13; i++) {
          int c = i * 16 + m16;
          if (c < 200) {
            #pragma unroll
            for (int r = 0; r < 4; r++)
              stgf[(lr + r) * 200 + c] = acc[s][i][r] + bias_v[i];
          }
        }
      }
      LDS_FENCE();
      const int rbase = rb + r8 * 8;
      uint4* g = (uint4*)(out + (size_t)(n0 + rbase) * HC);
      const uint4* sv = (const uint4*)stgf;
      for (int idx = lane; idx < 400; idx += 64)       // 8 rows * 50 uint4
        if (rbase + idx / 50 < nrows) g[idx] = sv[idx];
    }
  }
}

// ---------------- edge kernel ----------------
// Block-coop phase B (R5); CSR-slot-ordered outputs (R7).  NEW (R8):
// batch-issued preloads kill the per-iteration dependent-gather serialization:
//   - v_b rows for phase D issued right after sync0 (in flight across A/B/C)
//   - msg loads issued before the cos computation (hidden under VALU)
// k/q fragments load inline in phase C (compiler schedules fine, R4 evidence).
// launch_bounds(256,3): don't force spills; LDS caps occupancy anyway.
__global__ __launch_bounds__(256, 3) void edge_gemm(
    const int* __restrict__ edge_index, const float* __restrict__ t,
    const float* __restrict__ last_update, const float* __restrict__ msg,
    const float* __restrict__ w_time, const float* __restrict__ b_time,
    const unsigned short* __restrict__ WeT,
    const unsigned short* __restrict__ q_b, const unsigned short* __restrict__ k_b,
    const unsigned short* __restrict__ v_b, const int* __restrict__ pos,
    unsigned short* __restrict__ v_e, float* __restrict__ exbuf)
{
  __shared__ __align__(16) unsigned short e_lds[64 * EW];   // 33 KB, reused ea -> e(padded)
  __shared__ int   src_s[64], dst_s[64], pos_s[64];
  __shared__ float rel_s[64], wt_s[TIME_DIM], bt_s[TIME_DIM];

  const int tid = threadIdx.x;
  const int e0 = blockIdx.x * 64;

  if (tid < TIME_DIM) { wt_s[tid] = w_time[tid]; bt_s[tid] = b_time[tid]; }
  else if (tid >= 128 && tid < 192) {
    int el = tid - 128; int e = e0 + el;
    int s = edge_index[e], d = edge_index[N_EDGES + e];
    src_s[el] = s; dst_s[el] = d;
    pos_s[el] = pos[e];
    rel_s[el] = fabsf(last_update[s] - t[e]);
  }
  __syncthreads();     // sync0: publishes src/dst/pos/rel/wt/bt

  const int lane = tid & 63, wave = tid >> 6;
  const int m16 = lane & 15, quad = lane >> 4;
  const int r0 = wave * 16;
  unsigned short* my = e_lds + r0 * EW;

  const int my_src = src_s[r0 + m16];
  const int my_dst = dst_s[r0 + m16];

  // ---- preload v_b rows for phase D (depends only on src_s).  13 guarded us4
  // gathers issued back-to-back: ~700cy L3 latency hides under phases A+B+C.
  us4 vpre[13];
  #pragma unroll
  for (int j = 0; j < 13; j++) {
    int idx = j * 64 + lane;                 // 16 rows * 50 us4 = 800 chunks
    if (idx < 800) {
      int row = idx / 50, c = (idx % 50) * 4;
      vpre[j] = *reinterpret_cast<const us4*>(&v_b[(size_t)src_s[r0 + row] * HC + c]);
    }
  }

  // ---- phase A: issue msg loads FIRST, compute cos under them, then write both.
  float4 mpre[7];
  #pragma unroll
  for (int j = 0; j < 7; j++) {
    int idx = j * 64 + lane;                 // 16 rows * 25 float4 = 400 chunks
    if (idx < 400) {
      int row = idx / 25, c4 = (idx % 25) * 4;
      mpre[j] = *reinterpret_cast<const float4*>(
          msg + (size_t)(e0 + r0 + row) * MSG_DIM + c4);
    }
  }
  // cos region: cols [0,100) = 16 rows * 25 us4 = 400 chunks (pure VALU + LDS store)
  #pragma unroll
  for (int j = 0; j < 7; j++) {
    int idx = j * 64 + lane;
    if (idx < 400) {
      int row = idx / 25, c4 = (idx % 25) * 4;
      float rel = rel_s[r0 + row];
      us4 o;
      o.x = f2b(fast_cos(rel * wt_s[c4 + 0] + bt_s[c4 + 0]));
      o.y = f2b(fast_cos(rel * wt_s[c4 + 1] + bt_s[c4 + 1]));
      o.z = f2b(fast_cos(rel * wt_s[c4 + 2] + bt_s[c4 + 2]));
      o.w = f2b(fast_cos(rel * wt_s[c4 + 3] + bt_s[c4 + 3]));
      *reinterpret_cast<us4*>(&my[row * EW + c4]) = o;
    }
  }
  // zero pad cols [200,224): 16 rows * 6 us4 = 96 chunks
  for (int idx = lane; idx < 96; idx += 64) {
    int row = idx / 6, c4 = 200 + (idx % 6) * 4;
    us4 z = {0, 0, 0, 0};
    *reinterpret_cast<us4*>(&my[row * EW + c4]) = z;
  }
  // write msg region cols [100,200)
  #pragma unroll
  for (int j = 0; j < 7; j++) {
    int idx = j * 64 + lane;
    if (idx < 400) {
      int row = idx / 25, c4 = (idx % 25) * 4;
      us4 o;
      o.x = f2b(mpre[j].x); o.y = f2b(mpre[j].y);
      o.z = f2b(mpre[j].z); o.w = f2b(mpre[j].w);
      *reinterpret_cast<us4*>(&my[row * EW + 100 + c4]) = o;
    }
  }
  __syncthreads();     // sync1: all 64 edge_attr rows visible to all waves

  // phase B: block-coop e = ea @ WeT.  wave owns nt = wave + 4*i; B-frag held in
  // registers across the 4 m-tiles (4x less WeT traffic).
  f32x4_t acc[4][4];   // [i_own][m_tile]
  #pragma unroll
  for (int i = 0; i < 4; i++)
    #pragma unroll
    for (int m = 0; m < 4; m++) acc[i][m] = (f32x4_t){0.f, 0.f, 0.f, 0.f};

  #pragma unroll
  for (int i = 0; i < 4; i++) {
    const int nt = wave + 4 * i;
    if (nt < 13) {
      for (int kc = 0; kc < 7; kc++) {
        bf16x8_t b = *reinterpret_cast<const bf16x8_t*>(
            &WeT[(nt * 16 + m16) * KP_EDGE + kc * 32 + quad * 8]);
        #pragma unroll
        for (int m = 0; m < 4; m++) {
          bf16x8_t a = *reinterpret_cast<const bf16x8_t*>(
              &e_lds[(m * 16 + m16) * EW + kc * 32 + quad * 8]);
          acc[i][m] = __builtin_amdgcn_mfma_f32_16x16x32_bf16(a, b, acc[i][m], 0, 0, 0);
        }
      }
    }
  }
  __syncthreads();     // sync2: all reads of edge_attr complete before in-place overwrite

  // writeback e (bf16) into head-padded layout: col c -> (c<100 ? c : c+28).
  // wave w writes its nt cols for ALL 64 rows.
  #pragma unroll
  for (int i = 0; i < 4; i++) {
    const int nt = wave + 4 * i;
    if (nt < 13) {
      int c = nt * 16 + m16;
      if (c < 200) {
        int pc = (c < 100) ? c : c + 28;
        #pragma unroll
        for (int m = 0; m < 4; m++)
          #pragma unroll
          for (int r = 0; r < 4; r++)
            e_lds[(m * 16 + quad * 4 + r) * EW + pc] = f2b(acc[i][m][r]);
      }
    }
  }
  // zero pads cols 100..127 and 228..255 of own rows (disjoint bytes from e-writes)
  for (int idx = lane; idx < 224; idx += 64) {  // 16 rows * 14 us4
    int row = idx / 14, j = idx % 14;
    int col = (j < 7) ? (100 + j * 4) : (228 + (j - 7) * 4);
    us4 z = {0, 0, 0, 0};
    *reinterpret_cast<us4*>(&my[row * EW + col]) = z;
  }
  __syncthreads();     // sync3: padded e complete

  // phase C: alpha via MFMA diagonal.  D[m][n] = q[dst_m] . (k[src_n] + e_n)
  f32x4_t dacc[2];
  dacc[0] = (f32x4_t){0.f, 0.f, 0.f, 0.f};
  dacc[1] = (f32x4_t){0.f, 0.f, 0.f, 0.f};
  #pragma unroll
  for (int h = 0; h < 2; h++) {
    #pragma unroll
    for (int kc = 0; kc < 4; kc++) {
      int ko = h * 128 + kc * 32 + quad * 8;
      bf16x8_t a  = *reinterpret_cast<const bf16x8_t*>(&q_b[(size_t)my_dst * PAD_HC + ko]);
      bf16x8_t kb = *reinterpret_cast<const bf16x8_t*>(&k_b[(size_t)my_src * PAD_HC + ko]);
      bf16x8_t eb = *reinterpret_cast<const bf16x8_t*>(&my[m16 * EW + ko]);
      dacc[h] = __builtin_amdgcn_mfma_f32_16x16x32_bf16(a, kb, dacc[h], 0, 0, 0);
      dacc[h] = __builtin_amdgcn_mfma_f32_16x16x32_bf16(a, eb, dacc[h], 0, 0, 0);
    }
  }
  if (quad == (m16 >> 2)) {
    int r = m16 & 3;
    size_t p = (size_t)pos_s[r0 + m16];
    exbuf[p * 2 + 0] = expf(dacc[0][r] * 0.1f);
    exbuf[p * 2 + 1] = expf(dacc[1][r] * 0.1f);
  }

  // phase D: v_e[pos[e]] = vpre + e   (compact 200 cols, bf16; v_b already in regs)
  #pragma unroll
  for (int j = 0; j < 13; j++) {
    int idx = j * 64 + lane;
    if (idx < 800) {
      int row = idx / 50, c = (idx % 50) * 4;
      int pc = (c < 100) ? c : c + 28;
      us4 ev = *reinterpret_cast<const us4*>(&my[row * EW + pc]);
      us4 o;
      o.x = f2b(b2f(ev.x) + b2f(vpre[j].x));
      o.y = f2b(b2f(ev.y) + b2f(vpre[j].y));
      o.z = f2b(b2f(ev.z) + b2f(vpre[j].z));
      o.w = f2b(b2f(ev.w) + b2f(vpre[j].w));
      *reinterpret_cast<us4*>(&v_e[(size_t)pos_s[r0 + row] * HC + c]) = o;
    }
  }
}

// ---------------- CSR build ----------------
__global__ __launch_bounds__(256) void hist_kernel(const int* __restrict__ edge_index,
                                                   int* __restrict__ deg)
{
  int e = blockIdx.x * 256 + threadIdx.x;
  if (e < N_EDGES) atomicAdd(&deg[edge_index[N_EDGES + e]], 1);
}

__global__ __launch_bounds__(256) void scan1(const int* __restrict__ deg,
                                             int* __restrict__ cursor, int* __restrict__ bsum)
{
  __shared__ int s[256];
  const int tid = threadIdx.x;
  const int base = blockIdx.x * 1024 + tid * 4;
  int v[4]; int sum = 0;
  #pragma unroll
  for (int j = 0; j < 4; j++) {
    int i = base + j;
    v[j] = (i < N_NODES) ? deg[i] : 0;
    sum += v[j];
  }
  s[tid] = sum; __syncthreads();
  for (int d = 1; d < 256; d <<= 1) {
    int y = (tid >= d) ? s[tid - d] : 0;
    __syncthreads();
    s[tid] += y;
    __syncthreads();
  }
  int excl = s[tid] - sum;
  if (tid == 255) bsum[blockIdx.x] = s[255];
  int run = excl;
  #pragma unroll
  for (int j = 0; j < 4; j++) {
    int i = base + j;
    if (i < N_NODES) cursor[i] = run;
    run += v[j];
  }
}

__global__ void scan2(int* __restrict__ bsum, int nb)
{
  if (threadIdx.x == 0) {
    int acc = 0;
    for (int i = 0; i < nb; i++) { int t = bsum[i]; bsum[i] = acc; acc += t; }
  }
}

__global__ __launch_bounds__(256) void scan3(int* __restrict__ cursor,
                                             const int* __restrict__ bsum)
{
  int i = blockIdx.x * 256 + threadIdx.x;
  if (i < N_NODES) cursor[i] += bsum[i >> 10];
}

// fill: assign each edge its CSR slot (grouped by dst); emits pos[e] only.
__global__ __launch_bounds__(256) void fill_csr(const int* __restrict__ edge_index,
                                                int* __restrict__ cursor, int* __restrict__ pos)
{
  int e = blockIdx.x * 256 + threadIdx.x;
  if (e < N_EDGES) {
    int p = atomicAdd(&cursor[edge_index[N_EDGES + e]], 1);
    pos[e] = p;
  }
}

// ---------------- gather: out[n] = skip + (1/d) * sum_e ex * v_e  ----------------
// v_e/exbuf are in CSR-slot order -> the deg-loop streams a CONTIGUOUS block
// [off*HC, (off+dg)*HC).  Single pass: accumulate unnormalized sums + denominator,
// divide once at the end (same fp32 accumulation as two-pass).
__global__ __launch_bounds__(256) void gather_out(
    const int* __restrict__ cursor /* = end offsets after fill */,
    const int* __restrict__ deg,
    const unsigned short* __restrict__ v_e, const float* __restrict__ exbuf,
    float* __restrict__ out)
{
  const int wave = threadIdx.x >> 6, lane = threadIdx.x & 63;
  const int n = blockIdx.x * 4 + wave;
  const int dg = deg[n];
  const int off = cursor[n] - dg;          // start offset (fill advanced cursor by dg)

  float d0 = 1e-16f, d1 = 1e-16f;
  const int c0 = lane, c1 = lane + 64, c2 = lane + 128, c3 = lane + 192;
  float a0 = 0.f, a1 = 0.f, a2 = 0.f, a3 = 0.f;
  for (int j = 0; j < dg; j++) {
    size_t p = (size_t)(off + j);
    float ex0 = exbuf[p * 2 + 0];
    float ex1 = exbuf[p * 2 + 1];
    d0 += ex0; d1 += ex1;
    const unsigned short* vr = v_e + p * HC;
    a0 += ((c0 < 100) ? ex0 : ex1) * b2f(vr[c0]);
    a1 += ((c1 < 100) ? ex0 : ex1) * b2f(vr[c1]);
    a2 += ex1 * b2f(vr[c2]);
    if (c3 < HC) a3 += ex1 * b2f(vr[c3]);
  }
  const float i0 = 1.f / d0, i1 = 1.f / d1;
  float* o = out + (size_t)n * HC;
  o[c0] += a0 * ((c0 < 100) ? i0 : i1);
  o[c1] += a1 * ((c1 < 100) ? i0 : i1);
  o[c2] += a2 * i1;
  if (c3 < HC) o[c3] += a3 * i1;
}

// ---------------- launch ----------------
extern "C" void kernel_launch(void* const* d_in, const int* in_sizes, int n_in,
                              void* d_out, int out_size, void* d_ws, size_t ws_size,
                              hipStream_t stream)
{
  const float* x           = (const float*)d_in[0];
  const float* last_update = (const float*)d_in[1];
  const int*   edge_index  = (const int*)  d_in[2];
  const float* t           = (const float*)d_in[3];
  const float* msg         = (const float*)d_in[4];
  const float* w_time      = (const float*)d_in[5];
  const float* b_time      = (const float*)d_in[6];
  const float* Wq = (const float*)d_in[7];  const float* bq = (const float*)d_in[8];
  const float* Wk = (const float*)d_in[9];  const float* bk = (const float*)d_in[10];
  const float* Wv = (const float*)d_in[11]; const float* bv = (const float*)d_in[12];
  const float* We = (const float*)d_in[13];
  const float* Ws = (const float*)d_in[14]; const float* bs = (const float*)d_in[15];
  float* out = (float*)d_out;

  char* ws = (char*)d_ws;
  size_t off = 0;
  auto alloc = [&](size_t bytes) -> void* {
    void* p = ws + off;
    off = (off + bytes + 255) & ~(size_t)255;
    return p;
  };
  unsigned short* W4T   = (unsigned short*)alloc((size_t)W4T_ELEMS * 2);
  unsigned short* WeT   = (unsigned short*)alloc((size_t)NP_EDGE * KP_EDGE * 2);
  float*          bias4 = (float*)         alloc((size_t)4 * 208 * 4);
  unsigned short* q_b   = (unsigned short*)alloc((size_t)N_NODES * PAD_HC * 2);
  unsigned short* k_b   = (unsigned short*)alloc((size_t)N_NODES * PAD_HC * 2);
  unsigned short* v_b   = (unsigned short*)alloc((size_t)N_NODES * HC * 2);
  unsigned short* v_e   = (unsigned short*)alloc((size_t)N_EDGES * HC * 2);
  float*          exbuf = (float*)         alloc((size_t)N_EDGES * 2 * 4);
  int*            deg   = (int*)           alloc((size_t)N_NODES * 4);
  int*            cursor= (int*)           alloc((size_t)N_NODES * 4);
  int*            bsum  = (int*)           alloc((size_t)128 * 4);
  int*            pos   = (int*)           alloc((size_t)N_EDGES * 4);
  // total ws use ~= 310 MB

  hipMemsetAsync(deg, 0, (size_t)N_NODES * 4, stream);

  {
    int total = W4T_ELEMS + NP_EDGE * KP_EDGE + 4 * 208;
    pack_weights<<<(total + 255) / 256, 256, 0, stream>>>(
        Wq, bq, Wk, bk, Wv, bv, We, Ws, bs, W4T, WeT, bias4);
  }
  hist_kernel<<<(N_EDGES + 255) / 256, 256, 0, stream>>>(edge_index, deg);
  const int nb = (N_NODES + 1023) / 1024;   // 98
  scan1<<<nb, 256, 0, stream>>>(deg, cursor, bsum);
  scan2<<<1, 64, 0, stream>>>(bsum, nb);
  scan3<<<(N_NODES + 255) / 256, 256, 0, stream>>>(cursor, bsum);
  fill_csr<<<(N_EDGES + 255) / 256, 256, 0, stream>>>(edge_index, cursor, pos);

  node_gemm<<<NCHUNK * 4, 256, 0, stream>>>(x, W4T, bias4, q_b, k_b, v_b, out);
  edge_gemm<<<N_EDGES / 64, 256, 0, stream>>>(
      edge_index, t, last_update, msg, w_time, b_time, WeT, q_b, k_b, v_b, pos,
      v_e, exbuf);
  gather_out<<<N_NODES / 4, 256, 0, stream>>>(cursor, deg, v_e, exbuf, out);
}

// Round 9
// 778.154 us; speedup vs baseline: 1.8641x; 1.0335x over previous
//
#include <hip/hip_runtime.h>
#include <math.h>

// ---------------- problem constants ----------------
#define N_NODES 100000
#define N_EDGES 400000
#define IN_CH   100
#define OUT_CH  100
#define HEADS   2
#define HC      200      // HEADS*OUT_CH
#define TIME_DIM 100
#define MSG_DIM  100
#define EDGE_DIM 200
// padded GEMM dims
#define KP_NODE 128      // IN_CH padded to mult of 32
#define KP_EDGE 224      // EDGE_DIM padded to mult of 32
#define NP_EDGE 208      // HC padded to mult of 16 (13 n-tiles)
#define PAD_HC  256      // q/k rows padded: head h at h*128, cols 100..127/228..255 zero
#define EW      264      // e_lds row stride in bf16 elems (528 B)
// node-gemm slab blocking: 4 slabs (q|k|v|skip) x 13 n-tiles (208 cols), 128-node chunks
#define NSLAB_ELEMS (13 * 16 * KP_NODE)   // 26624 bf16 per slab
#define W4T_ELEMS   (4 * NSLAB_ELEMS)     // 106496
#define M_CHUNK 128
#define NCHUNK  782                        // ceil(100000/128)

typedef __attribute__((ext_vector_type(8))) short bf16x8_t;
typedef __attribute__((ext_vector_type(4))) float f32x4_t;

struct __align__(8) us4 { unsigned short x, y, z, w; };

static __device__ __forceinline__ float b2f(unsigned short u){
  union { float f; unsigned int i; } v; v.i = ((unsigned int)u) << 16; return v.f;
}
static __device__ __forceinline__ unsigned short f2b(float f){
  union { float f; unsigned int i; } v; v.f = f;
  unsigned int x = v.i;
  return (unsigned short)((x + 0x7fffu + ((x >> 16) & 1u)) >> 16);
}

// cos via HW: v_cos_f32 takes revolutions; v_fract reduces to [0,1).
// Error ~ |x|*2^-24 rad (<3e-4 here) -- far below the bf16 quantization of edge_attr.
static __device__ __forceinline__ float fast_cos(float x){
  float r = x * 0.15915494309189535f;          // x / (2*pi)
  r = __builtin_amdgcn_fractf(r);              // v_fract_f32
  return __builtin_amdgcn_cosf(r);             // v_cos_f32
}

// exp via HW: v_exp_f32 computes 2^x; pre-scale by log2(e).
static __device__ __forceinline__ float fast_exp(float x){
  float r;
  asm("v_exp_f32 %0, %1" : "=v"(r) : "v"(x * 1.4426950408889634f));
  return r;
}

// intra-wave LDS ordering without a barrier (and, critically, without the
// vmcnt(0) drain that __syncthreads() implies on gfx950).
// sched_barrier(0) after the waitcnt pins it in the schedule (guide rule #18).
#define LDS_FENCE() do { \
  asm volatile("s_waitcnt lgkmcnt(0)" ::: "memory"); \
  __builtin_amdgcn_sched_barrier(0); \
} while (0)

// ---------------- pack weights ----------------
// W4T: [slab][tile i][j 0..15][k 0..127] bf16, slab = q|k|v|skip, col = i*16+j (208, top 8 zero)
// bias4: [slab][208] fp32
__global__ __launch_bounds__(256) void pack_weights(
    const float* __restrict__ Wq, const float* __restrict__ bq,
    const float* __restrict__ Wk, const float* __restrict__ bk,
    const float* __restrict__ Wv, const float* __restrict__ bv,
    const float* __restrict__ We, const float* __restrict__ Ws, const float* __restrict__ bs,
    unsigned short* __restrict__ W4T, unsigned short* __restrict__ WeT,
    float* __restrict__ bias4)
{
  int idx = blockIdx.x * 256 + threadIdx.x;
  if (idx < W4T_ELEMS) {
    int row = idx >> 7;          // 0..831 = t*16 + j
    int k   = idx & 127;
    int t = row >> 4, j = row & 15;
    int slab = t / 13, i = t % 13;
    int col = i * 16 + j;        // 0..207
    float v = 0.f;
    if (k < IN_CH && col < HC) {
      const float* W = (slab == 0) ? Wq : (slab == 1) ? Wk : (slab == 2) ? Wv : Ws;
      v = W[k * HC + col];
    }
    W4T[idx] = f2b(v);
    return;
  }
  int j = idx - W4T_ELEMS;
  if (j < NP_EDGE * KP_EDGE) {                 // WeT[n][k]
    int n = j / KP_EDGE, k = j % KP_EDGE;
    float v = 0.f;
    if (n < HC && k < EDGE_DIM) v = We[k * HC + n];
    WeT[j] = f2b(v);
    return;
  }
  j -= NP_EDGE * KP_EDGE;
  if (j < 4 * 208) {
    int slab = j / 208, col = j % 208;
    const float* B = (slab == 0) ? bq : (slab == 1) ? bk : (slab == 2) ? bv : bs;
    bias4[j] = (col < HC) ? B[col] : 0.f;
  }
}

// ---------------- node GEMM: 128-node chunk x one 208-col slab per block ----------------
// blockIdx = chunk*4 + slab; 4 waves each own 32 rows.  Fully wave-private:
// each wave stages its own 32 x-rows, computes, and uses its own 8.7 KB slice
// of smem for the epilogue -> ZERO barriers (only intra-wave lgkmcnt fences).
__global__ __launch_bounds__(256) void node_gemm(
    const float* __restrict__ x, const unsigned short* __restrict__ W4T,
    const float* __restrict__ bias4,
    unsigned short* __restrict__ q_b, unsigned short* __restrict__ k_b,
    unsigned short* __restrict__ v_b, float* __restrict__ out)
{
  __shared__ __align__(16) unsigned char smem[34816];  // xt[128][136] bf16, per-wave reuse
  unsigned short* xt = (unsigned short*)smem;

  const int tid   = threadIdx.x;
  const int slab  = blockIdx.x & 3;
  const int chunk = blockIdx.x >> 2;
  const int n0    = chunk * M_CHUNK;
  const int nrows = (N_NODES - n0 < M_CHUNK) ? (N_NODES - n0) : M_CHUNK;

  const int lane = tid & 63, wave = tid >> 6;
  const int m16 = lane & 15, quad = lane >> 4;
  const int rb = wave * 32;

  // stage OWN 32 x-rows (float4 loads -> packed us4 LDS stores), zero-pad cols 100..127
  for (int idx = lane; idx < 800; idx += 64) {         // 32 rows * 25 float4
    int r = idx / 25, j = (idx % 25) * 4;
    int gr = rb + r;
    unsigned short* dst = xt + gr * 136 + j;
    us4 o;
    if (gr < nrows) {
      float4 xv = *reinterpret_cast<const float4*>(x + (size_t)(n0 + gr) * IN_CH + j);
      o.x = f2b(xv.x); o.y = f2b(xv.y); o.z = f2b(xv.z); o.w = f2b(xv.w);
    } else {
      o.x = o.y = o.z = o.w = 0;
    }
    *reinterpret_cast<us4*>(dst) = o;
  }
  for (int idx = lane; idx < 224; idx += 64) {         // 32 rows * 7 us4 pad
    int r = idx / 7, j = idx % 7;
    us4 z = {0, 0, 0, 0};
    *reinterpret_cast<us4*>(&xt[(rb + r) * 136 + 100 + j * 4]) = z;
  }
  LDS_FENCE();

  float bias_v[13];
  #pragma unroll
  for (int i = 0; i < 13; i++) bias_v[i] = bias4[slab * 208 + i * 16 + m16];

  f32x4_t acc[2][13];
  #pragma unroll
  for (int s = 0; s < 2; s++)
    #pragma unroll
    for (int i = 0; i < 13; i++) acc[s][i] = (f32x4_t){0.f, 0.f, 0.f, 0.f};

  const unsigned short* Wp = W4T + (size_t)slab * NSLAB_ELEMS;
  for (int kc = 0; kc < 4; kc++) {
    bf16x8_t a0 = *reinterpret_cast<const bf16x8_t*>(&xt[(rb + m16) * 136 + kc * 32 + quad * 8]);
    bf16x8_t a1 = *reinterpret_cast<const bf16x8_t*>(&xt[(rb + 16 + m16) * 136 + kc * 32 + quad * 8]);
    #pragma unroll
    for (int i = 0; i < 13; i++) {
      bf16x8_t b = *reinterpret_cast<const bf16x8_t*>(
          &Wp[(size_t)(i * 16 + m16) * KP_NODE + kc * 32 + quad * 8]);
      acc[0][i] = __builtin_amdgcn_mfma_f32_16x16x32_bf16(a0, b, acc[0][i], 0, 0, 0);
      acc[1][i] = __builtin_amdgcn_mfma_f32_16x16x32_bf16(a1, b, acc[1][i], 0, 0, 0);
    }
  }

  // epilogue: per-wave private staging in own xt slice (32*136 shorts = 8704 B)
  unsigned short* stg  = xt + rb * 136;
  float*          stgf = (float*)stg;

  if (slab < 2) {
    // q or k: head-padded [*, 256] bf16, 2 sub-rounds of 16 rows (8 KB each)
    unsigned short* gb = (slab == 0) ? q_b : k_b;
    for (int s = 0; s < 2; s++) {
      LDS_FENCE();
      for (int idx = lane; idx < 224; idx += 64) {     // zero pads: 16 rows * 14 us4
        int r = idx / 14, j = idx % 14;
        int col = (j < 7) ? (100 + j * 4) : (228 + (j - 7) * 4);
        us4 z = {0, 0, 0, 0};
        *reinterpret_cast<us4*>(&stg[r * 256 + col]) = z;
      }
      #pragma unroll
      for (int i = 0; i < 13; i++) {
        int c = i * 16 + m16;
        if (c < 200) {
          int pc = (c < 100) ? c : c + 28;
          #pragma unroll
          for (int r = 0; r < 4; r++)
            stg[(quad * 4 + r) * 256 + pc] = f2b(acc[s][i][r] + bias_v[i]);
        }
      }
      LDS_FENCE();
      const int rbase = rb + s * 16;
      uint4* g = (uint4*)(gb + (size_t)(n0 + rbase) * PAD_HC);
      const uint4* sv = (const uint4*)stg;
      for (int idx = lane; idx < 512; idx += 64)       // 16 rows * 32 uint4
        if (rbase + (idx >> 5) < nrows) g[idx] = sv[idx];
    }
  } else if (slab == 2) {
    // v: compact [*, 200] bf16, 2 sub-rounds of 16 rows (6.4 KB each)
    for (int s = 0; s < 2; s++) {
      LDS_FENCE();
      #pragma unroll
      for (int i = 0; i < 13; i++) {
        int c = i * 16 + m16;
        if (c < 200) {
          #pragma unroll
          for (int r = 0; r < 4; r++)
            stg[(quad * 4 + r) * 200 + c] = f2b(acc[s][i][r] + bias_v[i]);
        }
      }
      LDS_FENCE();
      const int rbase = rb + s * 16;
      uint4* g = (uint4*)(v_b + (size_t)(n0 + rbase) * HC);
      const uint4* sv = (const uint4*)stg;
      for (int idx = lane; idx < 400; idx += 64)       // 16 rows * 25 uint4
        if (rbase + idx / 25 < nrows) g[idx] = sv[idx];
    }
  } else {
    // skip/out: compact [*, 200] fp32, 4 sub-rounds of 8 rows (6.4 KB each)
    for (int r8 = 0; r8 < 4; r8++) {
      const int s = r8 >> 1;
      LDS_FENCE();
      if ((quad >> 1) == (r8 & 1)) {
        int lr = (quad & 1) * 4;
        #pragma unroll
        for (int i = 0; i < 13; i++) {
          int c = i * 16 + m16;
          if (c < 200) {
            #pragma unroll
            for (int r = 0; r < 4; r++)
              stgf[(lr + r) * 200 + c] = acc[s][i][r] + bias_v[i];
          }
        }
      }
      LDS_FENCE();
      const int rbase = rb + r8 * 8;
      uint4* g = (uint4*)(out + (size_t)(n0 + rbase) * HC);
      const uint4* sv = (const uint4*)stgf;
      for (int idx = lane; idx < 400; idx += 64)       // 8 rows * 50 uint4
        if (rbase + idx / 50 < nrows) g[idx] = sv[idx];
    }
  }
}

// ---------------- edge kernel ----------------
// R9: edges processed in CSR-SLOT ORDER (e = csr[slot]).  Consecutive slots share
// dst (avg degree 4) -> q_b gathers hit L1/L2 (~4x less q traffic), and v_e/exbuf
// writes are fully sequential (no scatter tax).  msg rows become gathered (small
// boundary cost).  Block-coop phase B (R5); batched preloads (R8).
__global__ __launch_bounds__(256, 4) void edge_gemm(
    const int* __restrict__ edge_index, const float* __restrict__ t,
    const float* __restrict__ last_update, const float* __restrict__ msg,
    const float* __restrict__ w_time, const float* __restrict__ b_time,
    const unsigned short* __restrict__ WeT,
    const unsigned short* __restrict__ q_b, const unsigned short* __restrict__ k_b,
    const unsigned short* __restrict__ v_b, const int* __restrict__ csr,
    unsigned short* __restrict__ v_e, float* __restrict__ exbuf)
{
  __shared__ __align__(16) unsigned short e_lds[64 * EW];   // 33 KB, reused ea -> e(padded)
  __shared__ int   e_s[64], src_s[64], dst_s[64];
  __shared__ float rel_s[64], wt_s[TIME_DIM], bt_s[TIME_DIM];

  const int tid = threadIdx.x;
  const int e0 = blockIdx.x * 64;            // SLOT base (CSR order)

  if (tid < TIME_DIM) { wt_s[tid] = w_time[tid]; bt_s[tid] = b_time[tid]; }
  else if (tid >= 128 && tid < 192) {
    int el = tid - 128;
    int e = csr[e0 + el];                    // slot -> edge
    int s = edge_index[e], d = edge_index[N_EDGES + e];
    e_s[el] = e; src_s[el] = s; dst_s[el] = d;
    rel_s[el] = fabsf(last_update[s] - t[e]);
  }
  __syncthreads();     // sync0: publishes e/src/dst/rel/wt/bt

  const int lane = tid & 63, wave = tid >> 6;
  const int m16 = lane & 15, quad = lane >> 4;
  const int r0 = wave * 16;
  unsigned short* my = e_lds + r0 * EW;

  const int my_src = src_s[r0 + m16];
  const int my_dst = dst_s[r0 + m16];

  // ---- preload v_b rows for phase D (depends only on src_s).  13 guarded us4
  // gathers issued back-to-back: one batched latency exposure instead of 13.
  us4 vpre[13];
  #pragma unroll
  for (int j = 0; j < 13; j++) {
    int idx = j * 64 + lane;                 // 16 rows * 50 us4 = 800 chunks
    if (idx < 800) {
      int row = idx / 50, c = (idx % 50) * 4;
      vpre[j] = *reinterpret_cast<const us4*>(&v_b[(size_t)src_s[r0 + row] * HC + c]);
    }
  }

  // ---- phase A: issue msg loads FIRST (per-row gather via e_s), cos under them.
  float4 mpre[7];
  #pragma unroll
  for (int j = 0; j < 7; j++) {
    int idx = j * 64 + lane;                 // 16 rows * 25 float4 = 400 chunks
    if (idx < 400) {
      int row = idx / 25, c4 = (idx % 25) * 4;
      mpre[j] = *reinterpret_cast<const float4*>(
          msg + (size_t)e_s[r0 + row] * MSG_DIM + c4);
    }
  }
  // cos region: cols [0,100) = 16 rows * 25 us4 = 400 chunks (pure VALU + LDS store)
  #pragma unroll
  for (int j = 0; j < 7; j++) {
    int idx = j * 64 + lane;
    if (idx < 400) {
      int row = idx / 25, c4 = (idx % 25) * 4;
      float rel = rel_s[r0 + row];
      us4 o;
      o.x = f2b(fast_cos(rel * wt_s[c4 + 0] + bt_s[c4 + 0]));
      o.y = f2b(fast_cos(rel * wt_s[c4 + 1] + bt_s[c4 + 1]));
      o.z = f2b(fast_cos(rel * wt_s[c4 + 2] + bt_s[c4 + 2]));
      o.w = f2b(fast_cos(rel * wt_s[c4 + 3] + bt_s[c4 + 3]));
      *reinterpret_cast<us4*>(&my[row * EW + c4]) = o;
    }
  }
  // zero pad cols [200,224): 16 rows * 6 us4 = 96 chunks
  for (int idx = lane; idx < 96; idx += 64) {
    int row = idx / 6, c4 = 200 + (idx % 6) * 4;
    us4 z = {0, 0, 0, 0};
    *reinterpret_cast<us4*>(&my[row * EW + c4]) = z;
  }
  // write msg region cols [100,200)
  #pragma unroll
  for (int j = 0; j < 7; j++) {
    int idx = j * 64 + lane;
    if (idx < 400) {
      int row = idx / 25, c4 = (idx % 25) * 4;
      us4 o;
      o.x = f2b(mpre[j].x); o.y = f2b(mpre[j].y);
      o.z = f2b(mpre[j].z); o.w = f2b(mpre[j].w);
      *reinterpret_cast<us4*>(&my[row * EW + 100 + c4]) = o;
    }
  }
  __syncthreads();     // sync1: all 64 edge_attr rows visible to all waves

  // phase B: block-coop e = ea @ WeT.  wave owns nt = wave + 4*i; B-frag held in
  // registers across the 4 m-tiles (4x less WeT traffic).
  f32x4_t acc[4][4];   // [i_own][m_tile]
  #pragma unroll
  for (int i = 0; i < 4; i++)
    #pragma unroll
    for (int m = 0; m < 4; m++) acc[i][m] = (f32x4_t){0.f, 0.f, 0.f, 0.f};

  #pragma unroll
  for (int i = 0; i < 4; i++) {
    const int nt = wave + 4 * i;
    if (nt < 13) {
      for (int kc = 0; kc < 7; kc++) {
        bf16x8_t b = *reinterpret_cast<const bf16x8_t*>(
            &WeT[(nt * 16 + m16) * KP_EDGE + kc * 32 + quad * 8]);
        #pragma unroll
        for (int m = 0; m < 4; m++) {
          bf16x8_t a = *reinterpret_cast<const bf16x8_t*>(
              &e_lds[(m * 16 + m16) * EW + kc * 32 + quad * 8]);
          acc[i][m] = __builtin_amdgcn_mfma_f32_16x16x32_bf16(a, b, acc[i][m], 0, 0, 0);
        }
      }
    }
  }
  __syncthreads();     // sync2: all reads of edge_attr complete before in-place overwrite

  // writeback e (bf16) into head-padded layout: col c -> (c<100 ? c : c+28).
  // wave w writes its nt cols for ALL 64 rows.
  #pragma unroll
  for (int i = 0; i < 4; i++) {
    const int nt = wave + 4 * i;
    if (nt < 13) {
      int c = nt * 16 + m16;
      if (c < 200) {
        int pc = (c < 100) ? c : c + 28;
        #pragma unroll
        for (int m = 0; m < 4; m++)
          #pragma unroll
          for (int r = 0; r < 4; r++)
            e_lds[(m * 16 + quad * 4 + r) * EW + pc] = f2b(acc[i][m][r]);
      }
    }
  }
  // zero pads cols 100..127 and 228..255 of own rows (disjoint bytes from e-writes)
  for (int idx = lane; idx < 224; idx += 64) {  // 16 rows * 14 us4
    int row = idx / 14, j = idx % 14;
    int col = (j < 7) ? (100 + j * 4) : (228 + (j - 7) * 4);
    us4 z = {0, 0, 0, 0};
    *reinterpret_cast<us4*>(&my[row * EW + col]) = z;
  }
  __syncthreads();     // sync3: padded e complete

  // phase C: alpha via MFMA diagonal.  D[m][n] = q[dst_m] . (k[src_n] + e_n)
  f32x4_t dacc[2];
  dacc[0] = (f32x4_t){0.f, 0.f, 0.f, 0.f};
  dacc[1] = (f32x4_t){0.f, 0.f, 0.f, 0.f};
  #pragma unroll
  for (int h = 0; h < 2; h++) {
    #pragma unroll
    for (int kc = 0; kc < 4; kc++) {
      int ko = h * 128 + kc * 32 + quad * 8;
      bf16x8_t a  = *reinterpret_cast<const bf16x8_t*>(&q_b[(size_t)my_dst * PAD_HC + ko]);
      bf16x8_t kb = *reinterpret_cast<const bf16x8_t*>(&k_b[(size_t)my_src * PAD_HC + ko]);
      bf16x8_t eb = *reinterpret_cast<const bf16x8_t*>(&my[m16 * EW + ko]);
      dacc[h] = __builtin_amdgcn_mfma_f32_16x16x32_bf16(a, kb, dacc[h], 0, 0, 0);
      dacc[h] = __builtin_amdgcn_mfma_f32_16x16x32_bf16(a, eb, dacc[h], 0, 0, 0);
    }
  }
  if (quad == (m16 >> 2)) {
    int r = m16 & 3;
    size_t p = (size_t)(e0 + r0 + m16);      // slot == output row (sequential)
    exbuf[p * 2 + 0] = fast_exp(dacc[0][r] * 0.1f);
    exbuf[p * 2 + 1] = fast_exp(dacc[1][r] * 0.1f);
  }

  // phase D: v_e[slot] = vpre + e   (compact 200 cols, bf16; sequential rows)
  #pragma unroll
  for (int j = 0; j < 13; j++) {
    int idx = j * 64 + lane;
    if (idx < 800) {
      int row = idx / 50, c = (idx % 50) * 4;
      int pc = (c < 100) ? c : c + 28;
      us4 ev = *reinterpret_cast<const us4*>(&my[row * EW + pc]);
      us4 o;
      o.x = f2b(b2f(ev.x) + b2f(vpre[j].x));
      o.y = f2b(b2f(ev.y) + b2f(vpre[j].y));
      o.z = f2b(b2f(ev.z) + b2f(vpre[j].z));
      o.w = f2b(b2f(ev.w) + b2f(vpre[j].w));
      *reinterpret_cast<us4*>(&v_e[(size_t)(e0 + r0 + row) * HC + c]) = o;
    }
  }
}

// ---------------- CSR build ----------------
__global__ __launch_bounds__(256) void hist_kernel(const int* __restrict__ edge_index,
                                                   int* __restrict__ deg)
{
  int e = blockIdx.x * 256 + threadIdx.x;
  if (e < N_EDGES) atomicAdd(&deg[edge_index[N_EDGES + e]], 1);
}

__global__ __launch_bounds__(256) void scan1(const int* __restrict__ deg,
                                             int* __restrict__ cursor, int* __restrict__ bsum)
{
  __shared__ int s[256];
  const int tid = threadIdx.x;
  const int base = blockIdx.x * 1024 + tid * 4;
  int v[4]; int sum = 0;
  #pragma unroll
  for (int j = 0; j < 4; j++) {
    int i = base + j;
    v[j] = (i < N_NODES) ? deg[i] : 0;
    sum += v[j];
  }
  s[tid] = sum; __syncthreads();
  for (int d = 1; d < 256; d <<= 1) {
    int y = (tid >= d) ? s[tid - d] : 0;
    __syncthreads();
    s[tid] += y;
    __syncthreads();
  }
  int excl = s[tid] - sum;
  if (tid == 255) bsum[blockIdx.x] = s[255];
  int run = excl;
  #pragma unroll
  for (int j = 0; j < 4; j++) {
    int i = base + j;
    if (i < N_NODES) cursor[i] = run;
    run += v[j];
  }
}

__global__ void scan2(int* __restrict__ bsum, int nb)
{
  if (threadIdx.x == 0) {
    int acc = 0;
    for (int i = 0; i < nb; i++) { int t = bsum[i]; bsum[i] = acc; acc += t; }
  }
}

__global__ __launch_bounds__(256) void scan3(int* __restrict__ cursor,
                                             const int* __restrict__ bsum)
{
  int i = blockIdx.x * 256 + threadIdx.x;
  if (i < N_NODES) cursor[i] += bsum[i >> 10];
}

// fill: csr[slot] = edge (slots grouped by dst node).
__global__ __launch_bounds__(256) void fill_csr(const int* __restrict__ edge_index,
                                                int* __restrict__ cursor, int* __restrict__ csr)
{
  int e = blockIdx.x * 256 + threadIdx.x;
  if (e < N_EDGES) {
    int p = atomicAdd(&cursor[edge_index[N_EDGES + e]], 1);
    csr[p] = e;
  }
}

// ---------------- gather: out[n] = skip + (1/d) * sum_e ex * v_e  ----------------
// v_e/exbuf are in CSR-slot order -> the deg-loop streams a CONTIGUOUS block
// [off*HC, (off+dg)*HC).  Single pass: accumulate unnormalized sums + denominator,
// divide once at the end (same fp32 accumulation as two-pass).
__global__ __launch_bounds__(256) void gather_out(
    const int* __restrict__ cursor /* = end offsets after fill */,
    const int* __restrict__ deg,
    const unsigned short* __restrict__ v_e, const float* __restrict__ exbuf,
    float* __restrict__ out)
{
  const int wave = threadIdx.x >> 6, lane = threadIdx.x & 63;
  const int n = blockIdx.x * 4 + wave;
  const int dg = deg[n];
  const int off = cursor[n] - dg;          // start offset (fill advanced cursor by dg)

  float d0 = 1e-16f, d1 = 1e-16f;
  const int c0 = lane, c1 = lane + 64, c2 = lane + 128, c3 = lane + 192;
  float a0 = 0.f, a1 = 0.f, a2 = 0.f, a3 = 0.f;
  for (int j = 0; j < dg; j++) {
    size_t p = (size_t)(off + j);
    float ex0 = exbuf[p * 2 + 0];
    float ex1 = exbuf[p * 2 + 1];
    d0 += ex0; d1 += ex1;
    const unsigned short* vr = v_e + p * HC;
    a0 += ((c0 < 100) ? ex0 : ex1) * b2f(vr[c0]);
    a1 += ((c1 < 100) ? ex0 : ex1) * b2f(vr[c1]);
    a2 += ex1 * b2f(vr[c2]);
    if (c3 < HC) a3 += ex1 * b2f(vr[c3]);
  }
  const float i0 = 1.f / d0, i1 = 1.f / d1;
  float* o = out + (size_t)n * HC;
  o[c0] += a0 * ((c0 < 100) ? i0 : i1);
  o[c1] += a1 * ((c1 < 100) ? i0 : i1);
  o[c2] += a2 * i1;
  if (c3 < HC) o[c3] += a3 * i1;
}

// ---------------- launch ----------------
extern "C" void kernel_launch(void* const* d_in, const int* in_sizes, int n_in,
                              void* d_out, int out_size, void* d_ws, size_t ws_size,
                              hipStream_t stream)
{
  const float* x           = (const float*)d_in[0];
  const float* last_update = (const float*)d_in[1];
  const int*   edge_index  = (const int*)  d_in[2];
  const float* t           = (const float*)d_in[3];
  const float* msg         = (const float*)d_in[4];
  const float* w_time      = (const float*)d_in[5];
  const float* b_time      = (const float*)d_in[6];
  const float* Wq = (const float*)d_in[7];  const float* bq = (const float*)d_in[8];
  const float* Wk = (const float*)d_in[9];  const float* bk = (const float*)d_in[10];
  const float* Wv = (const float*)d_in[11]; const float* bv = (const float*)d_in[12];
  const float* We = (const float*)d_in[13];
  const float* Ws = (const float*)d_in[14]; const float* bs = (const float*)d_in[15];
  float* out = (float*)d_out;

  char* ws = (char*)d_ws;
  size_t off = 0;
  auto alloc = [&](size_t bytes) -> void* {
    void* p = ws + off;
    off = (off + bytes + 255) & ~(size_t)255;
    return p;
  };
  unsigned short* W4T   = (unsigned short*)alloc((size_t)W4T_ELEMS * 2);
  unsigned short* WeT   = (unsigned short*)alloc((size_t)NP_EDGE * KP_EDGE * 2);
  float*          bias4 = (float*)         alloc((size_t)4 * 208 * 4);
  unsigned short* q_b   = (unsigned short*)alloc((size_t)N_NODES * PAD_HC * 2);
  unsigned short* k_b   = (unsigned short*)alloc((size_t)N_NODES * PAD_HC * 2);
  unsigned short* v_b   = (unsigned short*)alloc((size_t)N_NODES * HC * 2);
  unsigned short* v_e   = (unsigned short*)alloc((size_t)N_EDGES * HC * 2);
  float*          exbuf = (float*)         alloc((size_t)N_EDGES * 2 * 4);
  int*            deg   = (int*)           alloc((size_t)N_NODES * 4);
  int*            cursor= (int*)           alloc((size_t)N_NODES * 4);
  int*            bsum  = (int*)           alloc((size_t)128 * 4);
  int*            csr   = (int*)           alloc((size_t)N_EDGES * 4);
  // total ws use ~= 310 MB

  hipMemsetAsync(deg, 0, (size_t)N_NODES * 4, stream);

  {
    int total = W4T_ELEMS + NP_EDGE * KP_EDGE + 4 * 208;
    pack_weights<<<(total + 255) / 256, 256, 0, stream>>>(
        Wq, bq, Wk, bk, Wv, bv, We, Ws, bs, W4T, WeT, bias4);
  }
  hist_kernel<<<(N_EDGES + 255) / 256, 256, 0, stream>>>(edge_index, deg);
  const int nb = (N_NODES + 1023) / 1024;   // 98
  scan1<<<nb, 256, 0, stream>>>(deg, cursor, bsum);
  scan2<<<1, 64, 0, stream>>>(bsum, nb);
  scan3<<<(N_NODES + 255) / 256, 256, 0, stream>>>(cursor, bsum);
  fill_csr<<<(N_EDGES + 255) / 256, 256, 0, stream>>>(edge_index, cursor, csr);

  node_gemm<<<NCHUNK * 4, 256, 0, stream>>>(x, W4T, bias4, q_b, k_b, v_b, out);
  edge_gemm<<<N_EDGES / 64, 256, 0, stream>>>(
      edge_index, t, last_update, msg, w_time, b_time, WeT, q_b, k_b, v_b, csr,
      v_e, exbuf);
  gather_out<<<N_NODES / 4, 256, 0, stream>>>(cursor, deg, v_e, exbuf, out);
}